// Round 13
// baseline (1582.302 us; speedup 1.0000x reference)
//
#include <hip/hip_runtime.h>
#include <hip/hip_bf16.h>
#include <math.h>

#define GN 10000
#define GNP 10112        // GN padded to 128
#define GE 160000
#define GT 4
#define GL 3

typedef __attribute__((ext_vector_type(8))) short short8;
typedef __attribute__((ext_vector_type(4))) float f32x4;
typedef unsigned short u16;
typedef unsigned int u32;

__device__ __forceinline__ u16 f2b(float f) {
  unsigned u = __float_as_uint(f);
  unsigned r = (u + 0x7FFFu + ((u >> 16) & 1u)) >> 16;
  return (u16)r;
}
__device__ __forceinline__ float b2f(u16 b) {
  return __uint_as_float(((unsigned)b) << 16);
}

__device__ __forceinline__ void gl_lds16(const void* g, void* l) {
  __builtin_amdgcn_global_load_lds(
      (const __attribute__((address_space(1))) void*)g,
      (__attribute__((address_space(3))) void*)l, 16, 0, 0);
}

// bijective XCD-aware block swizzle (8 XCDs), works for any nwg
__device__ __forceinline__ int xcd_swz(int orig, int nwg) {
  int q = nwg >> 3, r = nwg & 7;
  int xcd = orig & 7, idx = orig >> 3;
  return (xcd < r ? xcd * (q + 1) : r * (q + 1) + (xcd - r) * q) + idx;
}

// ---------------------------------------------------------------------------
// fp32 tiled GEMM, z-batched over towers (post-W2 only; N=K=32)
// ---------------------------------------------------------------------------
__global__ __launch_bounds__(256) void gemmz_k(
    const float* __restrict__ A0, const float* __restrict__ B0,
    const float* __restrict__ bias0, u16* __restrict__ Cv,
    int M, int N, int K, int lda, int ldb, int ldc,
    size_t aZ, size_t btZ, size_t bZ, int cCol)
{
  __shared__ float As[16][65];
  __shared__ float Bs[16][65];
  const int z = blockIdx.z;
  const float* A = A0 + (size_t)z * aZ;
  const float* B = B0 + (size_t)z * btZ;
  const float* bias = bias0 + (size_t)z * bZ;
  const int tid = threadIdx.x;
  const int brow = blockIdx.y * 64;
  const int tr = ((tid >> 4) & 15) << 2;
  const int tc = (tid & 15) << 2;
  float acc[4][4] = {{0.f}};

  for (int k0 = 0; k0 < K; k0 += 16) {
    for (int i = tid; i < 64 * 16; i += 256) {
      int r = i >> 4, c = i & 15;
      int gr = brow + r, gk = k0 + c;
      float v = 0.f;
      if (gr < M && gk < K) v = A[(size_t)gr * lda + gk];
      As[c][r] = v;
    }
    for (int i = tid; i < 16 * 64; i += 256) {
      int r = i >> 6, c = i & 63;
      int gk = k0 + r;
      Bs[r][c] = (gk < K && c < N) ? B[(size_t)gk * ldb + c] : 0.f;
    }
    __syncthreads();
#pragma unroll
    for (int kk = 0; kk < 16; ++kk) {
      float a[4], b[4];
#pragma unroll
      for (int i = 0; i < 4; ++i) a[i] = As[kk][tr + i];
#pragma unroll
      for (int j = 0; j < 4; ++j) b[j] = Bs[kk][tc + j];
#pragma unroll
      for (int i = 0; i < 4; ++i)
#pragma unroll
        for (int j = 0; j < 4; ++j) acc[i][j] += a[i] * b[j];
    }
    __syncthreads();
  }

#pragma unroll
  for (int i = 0; i < 4; ++i) {
    int gr = brow + tr + i;
    if (gr >= M) continue;
#pragma unroll
    for (int j = 0; j < 4; ++j) {
      int gc = tc + j;
      if (gc >= N) continue;
      Cv[(size_t)gr * ldc + z * cCol + gc] = f2b(acc[i][j] + bias[gc]);
    }
  }
}

// ---------------------------------------------------------------------------
// bf16 MFMA GEMM, 64x64 tile base (med_ea uses it with epilogue extension)
// ---------------------------------------------------------------------------
template<bool RELU, bool OUTB, bool EAFILL>
__global__ __launch_bounds__(256) void mgemm_k(
    const u16* __restrict__ A,
    const u16* __restrict__ Bt, const float* __restrict__ bias,
    void* __restrict__ Cv,
    int M, int N, int K, int lda, int ldc,
    const float* __restrict__ ea, long e0)
{
  __shared__ u16 As[64 * 64];
  __shared__ u16 Bs[64 * 64];
  const int tid = threadIdx.x;
  const int brow = blockIdx.y * 64, bcol = blockIdx.x * 64;
  const int wid = tid >> 6, lane = tid & 63;
  const int wr = wid >> 1, wc = wid & 1;
  const int lrow = lane & 15, lk8 = (lane >> 4) * 8;

  f32x4 acc[2][2] = {};

  for (int k0 = 0; k0 < K; k0 += 64) {
#pragma unroll
    for (int s = 0; s < 2; ++s) {
      int c = tid + s * 256;
      int r = c >> 3, kq = (c & 7) * 8;
      const u16* sp = A + (size_t)(brow + r) * lda + k0 + kq;
      short8 v = *(const short8*)sp;
      int byt = (r * 128 + kq * 2) ^ ((r & 7) << 4);
      *(short8*)((char*)As + byt) = v;
    }
#pragma unroll
    for (int s = 0; s < 2; ++s) {
      int c = tid + s * 256;
      int r = c >> 3, kq = (c & 7) * 8;
      const u16* sp = Bt + (size_t)(bcol + r) * K + k0 + kq;
      short8 v = *(const short8*)sp;
      int byt = (r * 128 + kq * 2) ^ ((r & 7) << 4);
      *(short8*)((char*)Bs + byt) = v;
    }
    __syncthreads();
#pragma unroll
    for (int ks = 0; ks < 2; ++ks) {
      short8 a[2], b[2];
#pragma unroll
      for (int m = 0; m < 2; ++m) {
        int r = wr * 32 + m * 16 + lrow;
        int kk = ks * 32 + lk8;
        int byt = (r * 128 + kk * 2) ^ ((r & 7) << 4);
        a[m] = *(const short8*)((const char*)As + byt);
      }
#pragma unroll
      for (int n = 0; n < 2; ++n) {
        int r = wc * 32 + n * 16 + lrow;
        int kk = ks * 32 + lk8;
        int byt = (r * 128 + kk * 2) ^ ((r & 7) << 4);
        b[n] = *(const short8*)((const char*)Bs + byt);
      }
#pragma unroll
      for (int m = 0; m < 2; ++m)
#pragma unroll
        for (int n = 0; n < 2; ++n)
          acc[m][n] = __builtin_amdgcn_mfma_f32_16x16x32_bf16(a[m], b[n], acc[m][n], 0, 0, 0);
    }
    __syncthreads();
  }

#pragma unroll
  for (int m = 0; m < 2; ++m)
#pragma unroll
    for (int n = 0; n < 2; ++n) {
      int col = bcol + wc * 32 + n * 16 + (lane & 15);
      float bv = bias[col];
#pragma unroll
      for (int j = 0; j < 4; ++j) {
        int row = brow + wr * 32 + m * 16 + (lane >> 4) * 4 + j;
        float v = acc[m][n][j] + bv;
        if (RELU) v = fmaxf(v, 0.f);
        if (OUTB) ((u16*)Cv)[(size_t)row * ldc + col] = f2b(v);
        else      ((float*)Cv)[(size_t)row * ldc + col] = v;
      }
    }
  if (EAFILL) {
    for (int i = tid; i < 64 * 64; i += 256) {
      int r = i >> 6, c = i & 63;
      ((u16*)Cv)[(size_t)(brow + r) * 128 + 64 + c] =
          f2b(ea[(size_t)(e0 + brow + r) * 64 + c]);
    }
  }
}

// ---------------------------------------------------------------------------
// bf16 MFMA GEMM, 64x64 tile, z-batched (postW1 over towers; fu2/fv2)
// ---------------------------------------------------------------------------
template<bool RELU, bool OUTB>
__global__ __launch_bounds__(256) void mgemm_z_k(
    const u16* __restrict__ A0,
    const u16* __restrict__ Bt0, const float* __restrict__ bias0,
    void* __restrict__ Cv,
    int M, int N, int K, int lda, int ldc,
    size_t aZ, size_t btZ, size_t bZ, size_t cZ)
{
  __shared__ u16 As[64 * 64];
  __shared__ u16 Bs[64 * 64];
  const int z = blockIdx.z;
  const u16* A = A0 + (size_t)z * aZ;
  const u16* Bt = Bt0 + (size_t)z * btZ;
  const float* bias = bias0 + (size_t)z * bZ;
  const int tid = threadIdx.x;
  const int brow = blockIdx.y * 64, bcol = blockIdx.x * 64;
  const int wid = tid >> 6, lane = tid & 63;
  const int wr = wid >> 1, wc = wid & 1;
  const int lrow = lane & 15, lk8 = (lane >> 4) * 8;

  f32x4 acc[2][2] = {};

  for (int k0 = 0; k0 < K; k0 += 64) {
#pragma unroll
    for (int s = 0; s < 2; ++s) {
      int c = tid + s * 256;
      int r = c >> 3, kq = (c & 7) * 8;
      const u16* sp = A + (size_t)(brow + r) * lda + k0 + kq;
      short8 v = *(const short8*)sp;
      int byt = (r * 128 + kq * 2) ^ ((r & 7) << 4);
      *(short8*)((char*)As + byt) = v;
    }
#pragma unroll
    for (int s = 0; s < 2; ++s) {
      int c = tid + s * 256;
      int r = c >> 3, kq = (c & 7) * 8;
      const u16* sp = Bt + (size_t)(bcol + r) * K + k0 + kq;
      short8 v = *(const short8*)sp;
      int byt = (r * 128 + kq * 2) ^ ((r & 7) << 4);
      *(short8*)((char*)Bs + byt) = v;
    }
    __syncthreads();
#pragma unroll
    for (int ks = 0; ks < 2; ++ks) {
      short8 a[2], b[2];
#pragma unroll
      for (int m = 0; m < 2; ++m) {
        int r = wr * 32 + m * 16 + lrow;
        int kk = ks * 32 + lk8;
        int byt = (r * 128 + kk * 2) ^ ((r & 7) << 4);
        a[m] = *(const short8*)((const char*)As + byt);
      }
#pragma unroll
      for (int n = 0; n < 2; ++n) {
        int r = wc * 32 + n * 16 + lrow;
        int kk = ks * 32 + lk8;
        int byt = (r * 128 + kk * 2) ^ ((r & 7) << 4);
        b[n] = *(const short8*)((const char*)Bs + byt);
      }
#pragma unroll
      for (int m = 0; m < 2; ++m)
#pragma unroll
        for (int n = 0; n < 2; ++n)
          acc[m][n] = __builtin_amdgcn_mfma_f32_16x16x32_bf16(a[m], b[n], acc[m][n], 0, 0, 0);
    }
    __syncthreads();
  }

#pragma unroll
  for (int m = 0; m < 2; ++m)
#pragma unroll
    for (int n = 0; n < 2; ++n) {
      int col = bcol + wc * 32 + n * 16 + (lane & 15);
      float bv = bias[col];
#pragma unroll
      for (int j = 0; j < 4; ++j) {
        int row = brow + wr * 32 + m * 16 + (lane >> 4) * 4 + j;
        float v = acc[m][n][j] + bv;
        if (RELU) v = fmaxf(v, 0.f);
        if (OUTB) ((u16*)Cv + (size_t)z * cZ)[(size_t)row * ldc + col] = f2b(v);
        else      ((float*)Cv + (size_t)z * cZ)[(size_t)row * ldc + col] = v;
      }
    }
}

// ---------------------------------------------------------------------------
// bf16 MFMA GEMM, 128x128 tile. Non-MUL: gl_lds staging (src-granule swizzle).
// MUL: reg-staged A.*A2 with dual gather. M%128==0, N%128==0, K%64==0.
// ---------------------------------------------------------------------------
template<bool RELU, bool GATHER, bool MUL, bool OUTB>
__global__ __launch_bounds__(256) void mg2_k(
    const u16* __restrict__ A, const u16* __restrict__ A2,
    const int* __restrict__ idx, const int* __restrict__ idx2,
    const u16* __restrict__ Bt, const float* __restrict__ bias,
    void* __restrict__ Cv,
    int M, int N, int K, int lda, int ldc)
{
  __shared__ u16 As[128 * 64];
  __shared__ u16 Bs[128 * 64];
  __shared__ int ridx[128];
  __shared__ int ridx2[128];
  const int tid = threadIdx.x;
  const int brow = blockIdx.y * 128, bcol = blockIdx.x * 128;
  const int wid = tid >> 6, lane = tid & 63;
  const int wr = wid >> 1, wc = wid & 1;
  const int lrow = lane & 15, lkg = lane >> 4;

  if (GATHER) {
    if (tid < 128) {
      ridx[tid] = idx[brow + tid];
      if (MUL) ridx2[tid] = idx2[brow + tid];
    }
    __syncthreads();
  }

  f32x4 acc[4][4] = {};

  const char* srcA[4];
  const char* srcB[4];
#pragma unroll
  for (int s = 0; s < 4; ++s) {
    int i = tid + s * 256;
    int r = i >> 3, g = i & 7;
    size_t grow = GATHER ? (size_t)ridx[r] : (size_t)(brow + r);
    int gq = (g ^ (r & 7)) * 8;
    srcA[s] = (const char*)(A + grow * lda + gq);
    srcB[s] = (const char*)(Bt + (size_t)(bcol + r) * K + gq);
  }

  for (int k0 = 0; k0 < K; k0 += 64) {
    if constexpr (!MUL) {
#pragma unroll
      for (int s = 0; s < 4; ++s)
        gl_lds16(srcA[s] + (size_t)k0 * 2, (char*)As + s * 4096 + wid * 1024);
#pragma unroll
      for (int s = 0; s < 4; ++s)
        gl_lds16(srcB[s] + (size_t)k0 * 2, (char*)Bs + s * 4096 + wid * 1024);
    } else {
#pragma unroll
      for (int s = 0; s < 4; ++s) {
        int i = tid + s * 256;
        int r = i >> 3, kq = (i & 7) * 8;
        size_t grow = GATHER ? (size_t)ridx[r] : (size_t)(brow + r);
        size_t grow2 = GATHER ? (size_t)ridx2[r] : (size_t)(brow + r);
        const u16* sp = A + grow * lda + k0 + kq;
        short8 v = *(const short8*)sp;
        const u16* sp2 = A2 + grow2 * lda + k0 + kq;
        short8 v2 = *(const short8*)sp2;
#pragma unroll
        for (int e = 0; e < 8; ++e)
          v[e] = (short)f2b(b2f((u16)v[e]) * b2f((u16)v2[e]));
        int byt = (r * 128 + kq * 2) ^ ((r & 7) << 4);
        *(short8*)((char*)As + byt) = v;
      }
#pragma unroll
      for (int s = 0; s < 4; ++s) {
        int i = tid + s * 256;
        int r = i >> 3, kq = (i & 7) * 8;
        const u16* sp = Bt + (size_t)(bcol + r) * K + k0 + kq;
        short8 v = *(const short8*)sp;
        int byt = (r * 128 + kq * 2) ^ ((r & 7) << 4);
        *(short8*)((char*)Bs + byt) = v;
      }
    }
    __syncthreads();
#pragma unroll
    for (int ks = 0; ks < 2; ++ks) {
      const int kb = ks * 64 + lkg * 16;
      short8 a[4], b[4];
#pragma unroll
      for (int m = 0; m < 4; ++m) {
        int r = wr * 64 + m * 16 + lrow;
        int byt = (r * 128 + kb) ^ ((r & 7) << 4);
        a[m] = *(const short8*)((const char*)As + byt);
      }
#pragma unroll
      for (int n = 0; n < 4; ++n) {
        int r = wc * 64 + n * 16 + lrow;
        int byt = (r * 128 + kb) ^ ((r & 7) << 4);
        b[n] = *(const short8*)((const char*)Bs + byt);
      }
#pragma unroll
      for (int m = 0; m < 4; ++m)
#pragma unroll
        for (int n = 0; n < 4; ++n)
          acc[m][n] = __builtin_amdgcn_mfma_f32_16x16x32_bf16(a[m], b[n], acc[m][n], 0, 0, 0);
    }
    __syncthreads();
  }

#pragma unroll
  for (int m = 0; m < 4; ++m)
#pragma unroll
    for (int n = 0; n < 4; ++n) {
      int col = bcol + wc * 64 + n * 16 + lrow;
      float bv = bias[col];
#pragma unroll
      for (int j = 0; j < 4; ++j) {
        int row = brow + wr * 64 + m * 16 + lkg * 4 + j;
        float v = acc[m][n][j] + bv;
        if (RELU) v = fmaxf(v, 0.f);
        if (OUTB) ((u16*)Cv)[(size_t)row * ldc + col] = f2b(v);
        else      ((float*)Cv)[(size_t)row * ldc + col] = v;
      }
    }
}

// ===========================================================================
// CONVF: fused conv message path per (128-edge tile, tower):
//  phase1: h = relu(ea[eidx]@EW_t + bc_t + XI_t[dst] + XJ_t[src]) -> LDS
//  phase2: msg = h @ W2_t + b2_t (K=128, h from LDS, FULL 4 k-steps) -> LDS
//  merge:  dst-sorted segmented reduce -> atomic sum/sumsq/max
// grid (Mc/128, T), XCD-swizzled blockIdx.x for L2 locality on XIJ gathers.
// ===========================================================================
__global__ __launch_bounds__(256) void convf_k(
    const u16* __restrict__ eab, const int* __restrict__ eidx,
    const int* __restrict__ src, const int* __restrict__ dst, long base,
    const u16* __restrict__ EWt, const float* __restrict__ bc,
    const u16* __restrict__ XIJ,
    const u16* __restrict__ W2t, const float* __restrict__ b2,
    float* __restrict__ sumb, float* __restrict__ sumsqb,
    unsigned* __restrict__ mxb, int Nn)
{
  __shared__ u16 AB[128 * 128];   // 32KB
  __shared__ u16 H[128 * 128];    // 32KB
  __shared__ int nid[128], sidm[128];
  u16* As = AB;
  u16* Bs = AB + 128 * 64;
  const int tid = threadIdx.x;
  const int brow = xcd_swz(blockIdx.x, gridDim.x) * 128;
  const int t = blockIdx.y;
  const int wid = tid >> 6, lane = tid & 63;
  const int wr = wid >> 1, wc = wid & 1;
  const int lrow = lane & 15, lkg = lane >> 4;

  __shared__ int eids[128];
  if (tid < 128) {
    int e = eidx[base + brow + tid];
    eids[tid] = e;
    nid[tid] = dst[e];
    sidm[tid] = src[e];
  }
  __syncthreads();

  // phase1 staging: eab tile (gathered rows, K=64) + EW_t tile
#pragma unroll
  for (int s = 0; s < 4; ++s) {
    int i = tid + s * 256;
    int r = i >> 3, g = i & 7;
    int gq = (g ^ (r & 7)) * 8;
    gl_lds16(eab + (size_t)eids[r] * 64 + gq, (char*)As + s * 4096 + wid * 1024);
  }
#pragma unroll
  for (int s = 0; s < 4; ++s) {
    int i = tid + s * 256;
    int r = i >> 3, g = i & 7;
    int gq = (g ^ (r & 7)) * 8;
    gl_lds16(EWt + (size_t)(t * 128 + r) * 64 + gq, (char*)Bs + s * 4096 + wid * 1024);
  }
  __syncthreads();

  f32x4 acc[4][4] = {};
#pragma unroll
  for (int ks = 0; ks < 2; ++ks) {
    const int kb = ks * 64 + lkg * 16;
    short8 a[4], b[4];
#pragma unroll
    for (int m = 0; m < 4; ++m) {
      int r = wr * 64 + m * 16 + lrow;
      int byt = (r * 128 + kb) ^ ((r & 7) << 4);
      a[m] = *(const short8*)((const char*)As + byt);
    }
#pragma unroll
    for (int n = 0; n < 4; ++n) {
      int r = wc * 64 + n * 16 + lrow;
      int byt = (r * 128 + kb) ^ ((r & 7) << 4);
      b[n] = *(const short8*)((const char*)Bs + byt);
    }
#pragma unroll
    for (int m = 0; m < 4; ++m)
#pragma unroll
      for (int n = 0; n < 4; ++n)
        acc[m][n] = __builtin_amdgcn_mfma_f32_16x16x32_bf16(a[m], b[n], acc[m][n], 0, 0, 0);
  }

  // epilogue: h = relu(acc + bc + XI[dst] + XJ[src]) -> H (swizzled, 256B rows)
#pragma unroll
  for (int m = 0; m < 4; ++m)
#pragma unroll
    for (int n = 0; n < 4; ++n) {
      int cl = wc * 64 + n * 16 + lrow;
      int col = t * 128 + cl;
      float bv = bc[col];
#pragma unroll
      for (int j = 0; j < 4; ++j) {
        int rl = wr * 64 + m * 16 + lkg * 4 + j;
        float v = acc[m][n][j] + bv
                + b2f(XIJ[(size_t)nid[rl] * 1024 + col])
                + b2f(XIJ[(size_t)sidm[rl] * 1024 + 512 + col]);
        int byt = (rl * 256 + cl * 2) ^ ((rl & 7) << 4);
        *(u16*)((char*)H + byt) = f2b(fmaxf(v, 0.f));
      }
    }

  // stage W2_t (128 out x 128 k) into AB
  __syncthreads();
#pragma unroll
  for (int s = 0; s < 8; ++s) {
    int i = tid + s * 256;
    int r = i >> 4, g = i & 15;
    int gs = (g & 8) | ((g & 7) ^ (r & 7));
    gl_lds16(W2t + (size_t)t * 16384 + (size_t)r * 128 + gs * 8,
             (char*)AB + s * 4096 + wid * 1024);
  }
  __syncthreads();

  // phase2: msg = H @ W2s^T, K=128 -> FULL 4 k-steps (32 elements each)
  f32x4 acc2[4][4] = {};
#pragma unroll
  for (int ks = 0; ks < 4; ++ks) {
    const int kb = ks * 64 + lkg * 16;
    short8 a[4], b[4];
#pragma unroll
    for (int m = 0; m < 4; ++m) {
      int r = wr * 64 + m * 16 + lrow;
      int byt = (r * 256 + kb) ^ ((r & 7) << 4);
      a[m] = *(const short8*)((const char*)H + byt);
    }
#pragma unroll
    for (int n = 0; n < 4; ++n) {
      int c = wc * 64 + n * 16 + lrow;
      int byt = (c * 256 + kb) ^ ((c & 7) << 4);
      b[n] = *(const short8*)((const char*)AB + byt);
    }
#pragma unroll
    for (int m = 0; m < 4; ++m)
#pragma unroll
      for (int n = 0; n < 4; ++n)
        acc2[m][n] = __builtin_amdgcn_mfma_f32_16x16x32_bf16(a[m], b[n], acc2[m][n], 0, 0, 0);
  }
  __syncthreads();   // H reads done

  // msg -> H (swizzled to avoid write conflicts; merge read uses same XOR)
#pragma unroll
  for (int m = 0; m < 4; ++m)
#pragma unroll
    for (int n = 0; n < 4; ++n) {
      int col = wc * 64 + n * 16 + lrow;
      float bv = b2[t * 128 + col];
#pragma unroll
      for (int j = 0; j < 4; ++j) {
        int row = wr * 64 + m * 16 + lkg * 4 + j;
        int byt = (row * 256 + col * 2) ^ ((row & 7) << 4);
        *(u16*)((char*)H + byt) = f2b(acc2[m][n][j] + bv);
      }
    }
  __syncthreads();

  // segmented merge: 256 thr = (col 0..127) x (half 0..1)
  {
    const int col = tid & 127, half = tid >> 7;
    const int r0 = half * 64;
    float* sb = sumb + (size_t)t * Nn * 128;
    float* qb = sumsqb + (size_t)t * Nn * 128;
    unsigned* xbp = mxb + (size_t)t * Nn * 128;
    int cur = nid[r0];
    float sacc = 0.f, qacc = 0.f, mxv = -INFINITY;
    for (int rr = 0; rr < 64; ++rr) {
      int row = r0 + rr;
      int nd = nid[row];
      if (nd != cur) {
        size_t o = (size_t)cur * 128 + col;
        atomicAdd(&sb[o], sacc);
        atomicAdd(&qb[o], qacc);
        unsigned ub = __float_as_uint(mxv);
        atomicMax(&xbp[o], (ub & 0x80000000u) ? ~ub : (ub | 0x80000000u));
        cur = nd; sacc = 0.f; qacc = 0.f; mxv = -INFINITY;
      }
      int byt = (row * 256 + col * 2) ^ ((row & 7) << 4);
      float v = b2f(*(const u16*)((const char*)H + byt));
      sacc += v; qacc += v * v; mxv = fmaxf(mxv, v);
    }
    size_t o = (size_t)cur * 128 + col;
    atomicAdd(&sb[o], sacc);
    atomicAdd(&qb[o], qacc);
    unsigned ub = __float_as_uint(mxv);
    atomicMax(&xbp[o], (ub & 0x80000000u) ? ~ub : (ub | 0x80000000u));
  }
}

// ===========================================================================
// EU fused: eu1 = relu(ecat@euW1^T + b1) (128x128, in LDS), then
// ea = eu1@euW2^T + b2 -> EAp (fp32) + eab (bf16). grid (Mc/128).
// ===========================================================================
__global__ __launch_bounds__(256) void eu_fused_k(
    const u16* __restrict__ C3b,
    const u16* __restrict__ euW1t, const float* __restrict__ eu_b1,
    const u16* __restrict__ euW2t, const float* __restrict__ eu_b2,
    float* __restrict__ EAp, u16* __restrict__ eab, long e0)
{
  __shared__ u16 SM[128 * 128];
  __shared__ u16 W2s[64 * 128];
  u16* As = SM;
  u16* Bs = SM + 128 * 64;
  const int tid = threadIdx.x;
  const int brow = blockIdx.x * 128;
  const int wid = tid >> 6, lane = tid & 63;
  const int wr = wid >> 1, wc = wid & 1;
  const int lrow = lane & 15, lkg = lane >> 4;

#pragma unroll
  for (int s = 0; s < 4; ++s) {
    int i = tid + s * 256;
    int r = i >> 4, g = i & 15;
    int gs = (g & 8) | ((g & 7) ^ (r & 7));
    gl_lds16(euW2t + (size_t)r * 128 + gs * 8, (char*)W2s + s * 4096 + wid * 1024);
  }

  const char* srcA[4];
  const char* srcB[4];
#pragma unroll
  for (int s = 0; s < 4; ++s) {
    int i = tid + s * 256;
    int r = i >> 3, g = i & 7;
    int gq = (g ^ (r & 7)) * 8;
    srcA[s] = (const char*)(C3b + (size_t)(brow + r) * 128 + gq);
    srcB[s] = (const char*)(euW1t + (size_t)r * 128 + gq);
  }

  f32x4 acc[4][4] = {};
  for (int k0 = 0; k0 < 128; k0 += 64) {
#pragma unroll
    for (int s = 0; s < 4; ++s)
      gl_lds16(srcA[s] + (size_t)k0 * 2, (char*)As + s * 4096 + wid * 1024);
#pragma unroll
    for (int s = 0; s < 4; ++s)
      gl_lds16(srcB[s] + (size_t)k0 * 2, (char*)Bs + s * 4096 + wid * 1024);
    __syncthreads();
#pragma unroll
    for (int ks = 0; ks < 2; ++ks) {
      const int kb = ks * 64 + lkg * 16;
      short8 a[4], b[4];
#pragma unroll
      for (int m = 0; m < 4; ++m) {
        int r = wr * 64 + m * 16 + lrow;
        int byt = (r * 128 + kb) ^ ((r & 7) << 4);
        a[m] = *(const short8*)((const char*)As + byt);
      }
#pragma unroll
      for (int n = 0; n < 4; ++n) {
        int r = wc * 64 + n * 16 + lrow;
        int byt = (r * 128 + kb) ^ ((r & 7) << 4);
        b[n] = *(const short8*)((const char*)Bs + byt);
      }
#pragma unroll
      for (int m = 0; m < 4; ++m)
#pragma unroll
        for (int n = 0; n < 4; ++n)
          acc[m][n] = __builtin_amdgcn_mfma_f32_16x16x32_bf16(a[m], b[n], acc[m][n], 0, 0, 0);
    }
    __syncthreads();
  }

#pragma unroll
  for (int m = 0; m < 4; ++m)
#pragma unroll
    for (int n = 0; n < 4; ++n) {
      int col = wc * 64 + n * 16 + lrow;
      float bv = eu_b1[col];
#pragma unroll
      for (int j = 0; j < 4; ++j) {
        int row = wr * 64 + m * 16 + lkg * 4 + j;
        float v = fmaxf(acc[m][n][j] + bv, 0.f);
        int byt = (row * 256 + col * 2) ^ ((row & 7) << 4);
        *(u16*)((char*)SM + byt) = f2b(v);
      }
    }
  __syncthreads();

  f32x4 acc2[2][4] = {};
#pragma unroll
  for (int ks = 0; ks < 4; ++ks) {
    const int kb = ks * 64 + lkg * 16;
    short8 a[2], b[4];
#pragma unroll
    for (int m = 0; m < 2; ++m) {
      int r = wid * 32 + m * 16 + lrow;
      int byt = (r * 256 + kb) ^ ((r & 7) << 4);
      a[m] = *(const short8*)((const char*)SM + byt);
    }
#pragma unroll
    for (int n = 0; n < 4; ++n) {
      int c = n * 16 + lrow;
      int byt = (c * 256 + kb) ^ ((c & 7) << 4);
      b[n] = *(const short8*)((const char*)W2s + byt);
    }
#pragma unroll
    for (int m = 0; m < 2; ++m)
#pragma unroll
      for (int n = 0; n < 4; ++n)
        acc2[m][n] = __builtin_amdgcn_mfma_f32_16x16x32_bf16(a[m], b[n], acc2[m][n], 0, 0, 0);
  }

#pragma unroll
  for (int m = 0; m < 2; ++m)
#pragma unroll
    for (int n = 0; n < 4; ++n) {
      int col = n * 16 + lrow;
      float bv = eu_b2[col];
#pragma unroll
      for (int j = 0; j < 4; ++j) {
        int row = wid * 32 + m * 16 + lkg * 4 + j;
        float v = acc2[m][n][j] + bv;
        size_t o = (size_t)(e0 + brow + row) * 64 + col;
        EAp[o] = v;
        eab[o] = f2b(v);
      }
    }
}

// ---------------------------------------------------------------------------
// Edge sort by dst (counting sort, shuffle scan)
// ---------------------------------------------------------------------------
__global__ void deg_kernel(const int* __restrict__ dst, int* __restrict__ deg, int E)
{
  int e = blockIdx.x * blockDim.x + threadIdx.x;
  if (e < E) atomicAdd(&deg[dst[e]], 1);
}

__global__ void scan_kernel(const int* __restrict__ deg, int* __restrict__ rowptr, int n)
{
  __shared__ int wsum[4];
  __shared__ int carry_s;
  const int tid = threadIdx.x, lane = tid & 63, wv = tid >> 6;
  if (tid == 0) carry_s = 0;
  __syncthreads();
  for (int base = 0; base < n; base += 256) {
    int i = base + tid;
    int v = (i < n) ? deg[i] : 0;
    int s = v;
#pragma unroll
    for (int off = 1; off < 64; off <<= 1) {
      int t = __shfl_up(s, off, 64);
      if (lane >= off) s += t;
    }
    if (lane == 63) wsum[wv] = s;
    __syncthreads();
    int wo = carry_s;
    for (int q = 0; q < wv; ++q) wo += wsum[q];
    int tot = carry_s + wsum[0] + wsum[1] + wsum[2] + wsum[3];
    __syncthreads();
    if (i < n) rowptr[i] = wo + s - v;
    if (tid == 0) carry_s = tot;
    __syncthreads();
  }
  if (threadIdx.x == 0) rowptr[n] = carry_s;
}

__global__ void scatter_kernel(const int* __restrict__ dst, int* __restrict__ cursor,
                               int* __restrict__ eidx, int E)
{
  int e = blockIdx.x * blockDim.x + threadIdx.x;
  if (e < E) {
    int p = atomicAdd(&cursor[dst[e]], 1);
    eidx[p] = e;
  }
}

// ---------------------------------------------------------------------------
// Weight prep
// ---------------------------------------------------------------------------
__global__ void wtb_kernel(const float* __restrict__ W, u16* __restrict__ Wt,
                           int K, int N, size_t wtStride)
{
  int b = blockIdx.y;
  const float* Wb = W + (size_t)b * K * N;
  u16* Wtb = Wt + (size_t)b * wtStride;
  for (int i = blockIdx.x * blockDim.x + threadIdx.x; i < K * N;
       i += gridDim.x * blockDim.x) {
    int k = i / N, n = i % N;
    Wtb[(size_t)n * K + k] = f2b(Wb[i]);
  }
}

__global__ void wtbsub_kernel(const float* __restrict__ W, u16* __restrict__ Wt,
                              int k0, size_t lStride)
{
  int b = blockIdx.y;
  int l = b >> 2, t = b & 3;
  const float* Wb = W + (size_t)b * 384 * 128 + (size_t)k0 * 128;
  u16* Wtb = Wt + (size_t)l * lStride + (size_t)t * 16384;
  for (int i = blockIdx.x * blockDim.x + threadIdx.x; i < 16384;
       i += gridDim.x * blockDim.x) {
    int n = i >> 7, k = i & 127;
    Wtb[(size_t)n * 128 + k] = f2b(Wb[(size_t)k * 128 + n]);
  }
}

__global__ void ewcomb_kernel(const float* __restrict__ encW,
                              const float* __restrict__ preW1, u16* __restrict__ EWt)
{
  int i = blockIdx.x * blockDim.x + threadIdx.x;
  if (i >= GL * 512 * 64) return;
  int l = i / (512 * 64);
  int rem = i % (512 * 64);
  int n = rem / 64, k = rem % 64;
  int t = n >> 7, o = n & 127;
  const float* eW = encW + (size_t)l * 64 * 128 + (size_t)k * 128;
  const float* pW = preW1 + ((size_t)(l * GT + t) * 384 + 256) * 128 + o;
  float s = 0.f;
  for (int j = 0; j < 128; ++j) s += eW[j] * pW[(size_t)j * 128];
  EWt[i] = f2b(s);
}

__global__ void bcomb_kernel(const float* __restrict__ encb,
                             const float* __restrict__ preb1,
                             const float* __restrict__ preW1, float* __restrict__ bc)
{
  int i = blockIdx.x * blockDim.x + threadIdx.x;
  if (i >= GL * 512) return;
  int l = i / 512, n = i % 512;
  int t = n >> 7, o = n & 127;
  const float* eb = encb + (size_t)l * 128;
  const float* pW = preW1 + ((size_t)(l * GT + t) * 384 + 256) * 128 + o;
  float s = preb1[(size_t)(l * GT + t) * 128 + o];
  for (int j = 0; j < 128; ++j) s += eb[j] * pW[(size_t)j * 128];
  bc[i] = s;
}

__global__ void biaspad_kernel(const float* __restrict__ b32, float* __restrict__ b64, int total)
{
  int i = blockIdx.x * blockDim.x + threadIdx.x;
  if (i >= total) return;
  b64[(i / 32) * 64 + (i % 32)] = b32[i];
}

__global__ void f2b_kernel(const float* __restrict__ in, u16* __restrict__ out, int n)
{
  int i = blockIdx.x * blockDim.x + threadIdx.x;
  if (i < n) out[i] = f2b(in[i]);
}

// ---------------------------------------------------------------------------
// Aggregator init
// ---------------------------------------------------------------------------
__global__ void agg_init_kernel(float* __restrict__ s, float* __restrict__ ss,
                                unsigned* __restrict__ mx, int total)
{
  int i = blockIdx.x * blockDim.x + threadIdx.x;
  if (i >= total) return;
  s[i] = 0.f; ss[i] = 0.f; mx[i] = 0x007FFFFFu;
}

// ---------------------------------------------------------------------------
// Finalize ALL towers -> catb4 bf16
// ---------------------------------------------------------------------------
__global__ void finalize_kernel(
    const float* __restrict__ sumb, const float* __restrict__ sumsqb,
    const unsigned* __restrict__ mxb, const int* __restrict__ rowptr,
    const float* __restrict__ x, u16* __restrict__ catb4, int Nn)
{
  int i = blockIdx.x * blockDim.x + threadIdx.x;
  if (i >= 4 * Nn * 128) return;
  int t = i / (Nn * 128);
  int j = i - t * Nn * 128;
  int n = j >> 7, c = j & 127;
  float cnt = fmaxf((float)(rowptr[n + 1] - rowptr[n]), 1.f);
  float mean = sumb[i] / cnt;
  float msq  = sumsqb[i] / cnt;
  float sd = sqrtf(fmaxf(msq - mean * mean, 0.f) + 1e-5f);
  unsigned u = mxb[i];
  unsigned bits = (u & 0x80000000u) ? (u & 0x7FFFFFFFu) : ~u;
  float mxv = __uint_as_float(bits);
  if ((bits & 0x7F800000u) == 0x7F800000u) mxv = 0.f;
  u16* cb = catb4 + ((size_t)t * GNP + n) * 512;
  cb[c]       = f2b(x[(size_t)n * 128 + c]);
  cb[128 + c] = f2b(mean);
  cb[256 + c] = f2b(mxv);
  cb[384 + c] = f2b(sd);
}

// ---------------------------------------------------------------------------
// GRU elementwise combine (+ bf16 copy of new h)
// ---------------------------------------------------------------------------
__global__ void gru_kernel(const float* __restrict__ gi, const float* __restrict__ gh,
                           const float* __restrict__ h, float* __restrict__ hout,
                           u16* __restrict__ xbo, int total)
{
  int i = blockIdx.x * blockDim.x + threadIdx.x;
  if (i >= total) return;
  int n = i >> 7, c = i & 127;
  const float* gin = gi + (size_t)n * 384;
  const float* ghn = gh + (size_t)n * 384;
  float ir = gin[c], iz = gin[128 + c], inn = gin[256 + c];
  float hr = ghn[c], hz = ghn[128 + c], hn = ghn[256 + c];
  float r = 1.f / (1.f + __expf(-(ir + hr)));
  float z = 1.f / (1.f + __expf(-(iz + hz)));
  float nn = tanhf(inn + r * hn);
  float v = (1.f - z) * nn + z * h[i];
  hout[i] = v;
  xbo[i] = f2b(v);
}

// ---------------------------------------------------------------------------
extern "C" void kernel_launch(void* const* d_in, const int* in_sizes, int n_in,
                              void* d_out, int out_size, void* d_ws, size_t ws_size,
                              hipStream_t stream)
{
  const int N_ = GN, E_ = GE, Np = GNP;

  const float* x_in   = (const float*)d_in[0];
  const int*   src    = (const int*)d_in[1];
  const int*   dst    = src + E_;
  const float* ea_in  = (const float*)d_in[2];
  const float* enc_W  = (const float*)d_in[3];
  const float* enc_b  = (const float*)d_in[4];
  const float* pre_W1 = (const float*)d_in[5];
  const float* pre_b1 = (const float*)d_in[6];
  const float* pre_W2 = (const float*)d_in[7];
  const float* pre_b2 = (const float*)d_in[8];
  const float* post_W1 = (const float*)d_in[9];
  const float* post_b1 = (const float*)d_in[10];
  const float* post_W2 = (const float*)d_in[11];
  const float* post_b2 = (const float*)d_in[12];
  const float* lin_W  = (const float*)d_in[13];
  const float* lin_b  = (const float*)d_in[14];
  const float* gru_Wi = (const float*)d_in[15];
  const float* gru_Wh = (const float*)d_in[16];
  const float* gru_bi = (const float*)d_in[17];
  const float* gru_bh = (const float*)d_in[18];
  const float* fcu_W1 = (const float*)d_in[19];
  const float* fcu_b1 = (const float*)d_in[20];
  const float* fcu_W2 = (const float*)d_in[21];
  const float* fcu_b2 = (const float*)d_in[22];
  const float* fcv_W1 = (const float*)d_in[23];
  const float* fcv_b1 = (const float*)d_in[24];
  const float* fcv_W2 = (const float*)d_in[25];
  const float* fcv_b2 = (const float*)d_in[26];
  const float* fc_W1  = (const float*)d_in[27];
  const float* fc_b1  = (const float*)d_in[28];
  const float* fc_W2  = (const float*)d_in[29];
  const float* fc_b2  = (const float*)d_in[30];
  const float* eu_W1  = (const float*)d_in[31];
  const float* eu_b1  = (const float*)d_in[32];
  const float* eu_W2  = (const float*)d_in[33];
  const float* eu_b2  = (const float*)d_in[34];

  // ---- workspace arena ----
  size_t used = 0;
  char* w = (char*)d_ws;
  auto alloc = [&](size_t bytes) {
    char* p = w + used;
    used += (bytes + 255) & ~(size_t)255;
    return p;
  };
  float*    sumb   = (float*)alloc((size_t)N_ * 512 * 4);
  float*    sumsqb = (float*)alloc((size_t)N_ * 512 * 4);
  unsigned* mxb    = (unsigned*)alloc((size_t)N_ * 512 * 4);
  float*    q1   = (float*)alloc((size_t)Np * 256 * 4);
  u16*      q2b  = (u16*)alloc((size_t)Np * 128 * 2);
  u16*      mbb  = (u16*)alloc((size_t)Np * 128 * 2);
  float*    gib  = (float*)alloc((size_t)Np * 384 * 4);
  float*    ghb  = (float*)alloc((size_t)Np * 384 * 4);
  float*    Hb   = (float*)alloc((size_t)N_ * 128 * 4);
  u16*      xb   = (u16*)alloc((size_t)Np * 128 * 2);
  u16*      catb4 = (u16*)alloc((size_t)4 * Np * 512 * 2);
  u16*      eab  = (u16*)alloc((size_t)E_ * 64 * 2);
  u16*      XIJ  = (u16*)alloc((size_t)Np * 1024 * 2);
  u16*      FUV1b = (u16*)alloc((size_t)Np * 512 * 2);
  u16*      FUVb  = (u16*)alloc((size_t)Np * 512 * 2);
  float*    zb   = (float*)alloc(1024 * 4);
  // weights
  u16* WIJt   = (u16*)alloc((size_t)GL * 1024 * 128 * 2);
  u16* EWt    = (u16*)alloc((size_t)GL * 512 * 64 * 2);
  float* bcomb = (float*)alloc((size_t)GL * 512 * 4);
  u16* preW2t = (u16*)alloc((size_t)GL * GT * 128 * 128 * 2);
  u16* postW1t = (u16*)alloc((size_t)GL * GT * 64 * 512 * 2);
  float* postb1p = (float*)alloc((size_t)GL * GT * 64 * 4);
  u16* linWt  = (u16*)alloc((size_t)GL * 128 * 128 * 2);
  u16* gruWit = (u16*)alloc((size_t)384 * 128 * 2);
  u16* gruWht = (u16*)alloc((size_t)384 * 128 * 2);
  u16* fuvW1t = (u16*)alloc((size_t)512 * 128 * 2);
  u16* fcuW2t = (u16*)alloc((size_t)256 * 256 * 2);
  u16* fcvW2t = (u16*)alloc((size_t)256 * 256 * 2);
  float* fuvb1 = (float*)alloc(512 * 4);
  float* fuvb2 = (float*)alloc(512 * 4);
  u16* fcW1t  = (u16*)alloc((size_t)256 * 256 * 2);
  u16* fcW2t  = (u16*)alloc((size_t)64 * 256 * 2);
  u16* euW1t  = (u16*)alloc((size_t)128 * 128 * 2);
  u16* euW2t  = (u16*)alloc((size_t)64 * 128 * 2);
  int* eidx   = (int*)alloc((size_t)E_ * 4);
  int* degb   = (int*)alloc((size_t)(N_ + 1) * 4);
  int* rowptr = (int*)alloc((size_t)(N_ + 1) * 4);
  int* cursor = (int*)alloc((size_t)(N_ + 1) * 4);

  // chunk arena: 768 B/row (edge chain only: C1b 512B + C3b 256B)
  size_t avail = (ws_size > used + 4096) ? (ws_size - used - 4096) : 0;
  long Ec = (long)(avail / 768);
  if (Ec > E_) Ec = E_;
  Ec &= ~255L;
  if (Ec < 256) return;   // ws too small: fail cleanly
  char* arena = alloc((size_t)Ec * 768);
  if (used > ws_size) return;
  const int nchunks = (int)((E_ + Ec - 1) / Ec);
  u16* C1b = (u16*)arena;                          // Ec x 256 bf16
  u16* C3b = (u16*)(arena + (size_t)Ec * 512);     // Ec x 128 bf16

  float* out = (float*)d_out;
  float* EAp = out + (size_t)N_ * 128;   // ea state lives in d_out

  // ---- one-time setup ----
  hipMemsetAsync(degb, 0, (size_t)N_ * 4, stream);
  deg_kernel<<<(E_ + 255) / 256, 256, 0, stream>>>(dst, degb, E_);
  scan_kernel<<<1, 256, 0, stream>>>(degb, rowptr, N_);
  hipMemcpyAsync(cursor, rowptr, (size_t)N_ * 4, hipMemcpyDeviceToDevice, stream);
  scatter_kernel<<<(E_ + 255) / 256, 256, 0, stream>>>(dst, cursor, eidx, E_);

  hipMemsetAsync(postW1t, 0, (size_t)GL * GT * 64 * 512 * 2, stream);
  hipMemsetAsync(postb1p, 0, (size_t)GL * GT * 64 * 4, stream);
  hipMemsetAsync(zb, 0, 1024 * 4, stream);
  {
    dim3 gb(48, GL);
    wtb_kernel<<<gb, 256, 0, stream>>>(lin_W, linWt, 128, 128, 128 * 128);
    dim3 gt(48, GL * GT);
    wtb_kernel<<<gt, 256, 0, stream>>>(pre_W2, preW2t, 128, 128, 128 * 128);
    wtb_kernel<<<gt, 256, 0, stream>>>(post_W1, postW1t, 512, 32, 64 * 512);
    dim3 gs(16, GL * GT);
    wtbsub_kernel<<<gs, 256, 0, stream>>>(pre_W1, WIJt, 0, 131072);
    wtbsub_kernel<<<gs, 256, 0, stream>>>(pre_W1, WIJt + 65536, 128, 131072);
    ewcomb_kernel<<<(GL * 512 * 64 + 255) / 256, 256, 0, stream>>>(enc_W, pre_W1, EWt);
    bcomb_kernel<<<(GL * 512 + 255) / 256, 256, 0, stream>>>(enc_b, pre_b1, pre_W1, bcomb);
    dim3 g1(48, 1);
    wtb_kernel<<<g1, 256, 0, stream>>>(gru_Wi, gruWit, 128, 384, 384 * 128);
    wtb_kernel<<<g1, 256, 0, stream>>>(gru_Wh, gruWht, 128, 384, 384 * 128);
    wtb_kernel<<<g1, 256, 0, stream>>>(fcu_W1, fuvW1t, 128, 256, 0);
    wtb_kernel<<<g1, 256, 0, stream>>>(fcv_W1, fuvW1t + 256 * 128, 128, 256, 0);
    wtb_kernel<<<g1, 256, 0, stream>>>(fcu_W2, fcuW2t, 256, 256, 0);
    wtb_kernel<<<g1, 256, 0, stream>>>(fcv_W2, fcvW2t, 256, 256, 0);
    wtb_kernel<<<g1, 256, 0, stream>>>(fc_W1, fcW1t, 256, 256, 0);
    wtb_kernel<<<g1, 256, 0, stream>>>(fc_W2, fcW2t, 256, 64, 0);
    wtb_kernel<<<g1, 256, 0, stream>>>(eu_W1, euW1t, 128, 128, 0);
    wtb_kernel<<<g1, 256, 0, stream>>>(eu_W2, euW2t, 128, 64, 0);
  }
  biaspad_kernel<<<(GL * GT * 32 + 255) / 256, 256, 0, stream>>>(
      post_b1, postb1p, GL * GT * 32);
  hipMemcpyAsync(fuvb1, fcu_b1, 256 * 4, hipMemcpyDeviceToDevice, stream);
  hipMemcpyAsync(fuvb1 + 256, fcv_b1, 256 * 4, hipMemcpyDeviceToDevice, stream);
  hipMemcpyAsync(fuvb2, fcu_b2, 256 * 4, hipMemcpyDeviceToDevice, stream);
  hipMemcpyAsync(fuvb2 + 256, fcv_b2, 256 * 4, hipMemcpyDeviceToDevice, stream);

  f2b_kernel<<<(N_ * 128 + 255) / 256, 256, 0, stream>>>(x_in, xb, N_ * 128);
  f2b_kernel<<<(E_ * 64 + 255) / 256, 256, 0, stream>>>(ea_in, eab, E_ * 64);

  const float* x_cur = x_in;
  const float* ea_cur = ea_in;

  for (int l = 0; l < GL; ++l) {
    // ---- PNA conv ----
    agg_init_kernel<<<(N_ * 512 + 255) / 256, 256, 0, stream>>>(sumb, sumsqb, mxb, N_ * 512);
    {
      dim3 gX(8, Np / 128);
      mg2_k<false, false, false, true><<<gX, 256, 0, stream>>>(
          xb, nullptr, nullptr, nullptr, WIJt + (size_t)l * 131072, zb,
          XIJ, Np, 1024, 128, 128, 1024);
    }
    {
      dim3 gC(E_ / 128, GT);
      convf_k<<<gC, 256, 0, stream>>>(
          eab, eidx, src, dst, 0,
          EWt + (size_t)l * 512 * 64, bcomb + (size_t)l * 512, XIJ,
          preW2t + (size_t)l * GT * 16384, pre_b2 + (size_t)l * 512,
          sumb, sumsqb, mxb, N_);
    }
    finalize_kernel<<<(4 * N_ * 128 + 255) / 256, 256, 0, stream>>>(
        sumb, sumsqb, mxb, rowptr, x_cur, catb4, N_);
    {
      dim3 gP1(1, Np / 64, 4);
      mgemm_z_k<true, false><<<gP1, 256, 0, stream>>>(
          catb4, postW1t + (size_t)l * GT * 64 * 512, postb1p + (size_t)l * GT * 64,
          q1, Np, 64, 512, 512, 64,
          (size_t)Np * 512, (size_t)64 * 512, 64, (size_t)Np * 64);
      dim3 gP2(1, (N_ + 63) / 64, 4);
      gemmz_k<<<gP2, 256, 0, stream>>>(
          q1, post_W2 + (size_t)l * GT * 32 * 32, post_b2 + (size_t)l * GT * 32,
          q2b, N_, 32, 32, 64, 32, 128,
          (size_t)Np * 64, (size_t)32 * 32, 32, 32);
    }
    {
      dim3 gL(1, Np / 128), gG(3, Np / 128);
      mg2_k<false, false, false, true><<<gL, 256, 0, stream>>>(
          q2b, nullptr, nullptr, nullptr, linWt + (size_t)l * 128 * 128,
          lin_b + (size_t)l * 128, mbb, Np, 128, 128, 128, 128);
      mg2_k<false, false, false, false><<<gG, 256, 0, stream>>>(
          mbb, nullptr, nullptr, nullptr, gruWit, gru_bi, gib, Np, 384, 128, 128, 384);
      mg2_k<false, false, false, false><<<gG, 256, 0, stream>>>(
          xb, nullptr, nullptr, nullptr, gruWht, gru_bh, ghb, Np, 384, 128, 128, 384);
    }
    gru_kernel<<<(N_ * 128 + 255) / 256, 256, 0, stream>>>(
        gib, ghb, x_cur, Hb, xb, N_ * 128);

    // ---- edge update: node-level FU/FV, lean per-edge chain ----
    {
      dim3 gF1(4, Np / 128);
      mg2_k<true, false, false, true><<<gF1, 256, 0, stream>>>(
          xb, nullptr, nullptr, nullptr, fuvW1t, fuvb1, FUV1b, Np, 512, 128, 128, 512);
      dim3 gF2(4, Np / 64, 2);
      mgemm_z_k<true, true><<<gF2, 256, 0, stream>>>(
          FUV1b, fcuW2t, fuvb2, FUVb, Np, 256, 256, 512, 256,
          (size_t)256, (size_t)256 * 256, 256, (size_t)Np * 256);
    }
    const u16* FUb = FUVb;
    const u16* FVb = FUVb + (size_t)Np * 256;
    for (int c = 0; c < nchunks; ++c) {
      long e0 = (long)c * Ec;
      int Mc = (int)(((long)E_ - e0 < Ec) ? ((long)E_ - e0) : Ec);
      dim3 g2m(2, Mc / 128), g64(1, Mc / 64);
      mg2_k<true, true, true, true><<<g2m, 256, 0, stream>>>(
          FUb, FVb, src + e0, dst + e0, fcW1t, fc_b1, C1b, Mc, 256, 256, 256, 256);
      mgemm_k<true, true, true><<<g64, 256, 0, stream>>>(
          C1b, fcW2t, fc_b2, C3b, Mc, 64, 256, 256, 128, ea_cur, e0);
      eu_fused_k<<<Mc / 128, 256, 0, stream>>>(
          C3b, euW1t, eu_b1, euW2t, eu_b2, EAp, eab, e0);
    }

    x_cur = Hb;
    ea_cur = EAp;
  }

  // outputs: [out (N*128) | ea (in place) | out (N*128)]
  hipMemcpyAsync(out, x_cur, (size_t)N_ * 128 * 4, hipMemcpyDeviceToDevice, stream);
  hipMemcpyAsync(out + (size_t)N_ * 128 + (size_t)E_ * 64, x_cur,
                 (size_t)N_ * 128 * 4, hipMemcpyDeviceToDevice, stream);
}

// Round 14
// 1489.517 us; speedup vs baseline: 1.0623x; 1.0623x over previous
//
#include <hip/hip_runtime.h>
#include <hip/hip_bf16.h>
#include <math.h>

#define GN 10000
#define GNP 10112        // GN padded to 128
#define GE 160000
#define GT 4
#define GL 3

typedef __attribute__((ext_vector_type(8))) short short8;
typedef __attribute__((ext_vector_type(4))) float f32x4;
typedef unsigned short u16;
typedef unsigned int u32;

__device__ __forceinline__ u16 f2b(float f) {
  unsigned u = __float_as_uint(f);
  unsigned r = (u + 0x7FFFu + ((u >> 16) & 1u)) >> 16;
  return (u16)r;
}
__device__ __forceinline__ float b2f(u16 b) {
  return __uint_as_float(((unsigned)b) << 16);
}

__device__ __forceinline__ void gl_lds16(const void* g, void* l) {
  __builtin_amdgcn_global_load_lds(
      (const __attribute__((address_space(1))) void*)g,
      (__attribute__((address_space(3))) void*)l, 16, 0, 0);
}

// bijective XCD-aware block swizzle (8 XCDs), works for any nwg
__device__ __forceinline__ int xcd_swz(int orig, int nwg) {
  int q = nwg >> 3, r = nwg & 7;
  int xcd = orig & 7, idx = orig >> 3;
  return (xcd < r ? xcd * (q + 1) : r * (q + 1) + (xcd - r) * q) + idx;
}

// ---------------------------------------------------------------------------
// fp32 tiled GEMM, z-batched over towers (post-W2 only; N=K=32)
// ---------------------------------------------------------------------------
__global__ __launch_bounds__(256) void gemmz_k(
    const float* __restrict__ A0, const float* __restrict__ B0,
    const float* __restrict__ bias0, u16* __restrict__ Cv,
    int M, int N, int K, int lda, int ldb, int ldc,
    size_t aZ, size_t btZ, size_t bZ, int cCol)
{
  __shared__ float As[16][65];
  __shared__ float Bs[16][65];
  const int z = blockIdx.z;
  const float* A = A0 + (size_t)z * aZ;
  const float* B = B0 + (size_t)z * btZ;
  const float* bias = bias0 + (size_t)z * bZ;
  const int tid = threadIdx.x;
  const int brow = blockIdx.y * 64;
  const int tr = ((tid >> 4) & 15) << 2;
  const int tc = (tid & 15) << 2;
  float acc[4][4] = {{0.f}};

  for (int k0 = 0; k0 < K; k0 += 16) {
    for (int i = tid; i < 64 * 16; i += 256) {
      int r = i >> 4, c = i & 15;
      int gr = brow + r, gk = k0 + c;
      float v = 0.f;
      if (gr < M && gk < K) v = A[(size_t)gr * lda + gk];
      As[c][r] = v;
    }
    for (int i = tid; i < 16 * 64; i += 256) {
      int r = i >> 6, c = i & 63;
      int gk = k0 + r;
      Bs[r][c] = (gk < K && c < N) ? B[(size_t)gk * ldb + c] : 0.f;
    }
    __syncthreads();
#pragma unroll
    for (int kk = 0; kk < 16; ++kk) {
      float a[4], b[4];
#pragma unroll
      for (int i = 0; i < 4; ++i) a[i] = As[kk][tr + i];
#pragma unroll
      for (int j = 0; j < 4; ++j) b[j] = Bs[kk][tc + j];
#pragma unroll
      for (int i = 0; i < 4; ++i)
#pragma unroll
        for (int j = 0; j < 4; ++j) acc[i][j] += a[i] * b[j];
    }
    __syncthreads();
  }

#pragma unroll
  for (int i = 0; i < 4; ++i) {
    int gr = brow + tr + i;
    if (gr >= M) continue;
#pragma unroll
    for (int j = 0; j < 4; ++j) {
      int gc = tc + j;
      if (gc >= N) continue;
      Cv[(size_t)gr * ldc + z * cCol + gc] = f2b(acc[i][j] + bias[gc]);
    }
  }
}

// ---------------------------------------------------------------------------
// bf16 MFMA GEMM, 64x64 tile base (med_ea uses it with epilogue extension)
// ---------------------------------------------------------------------------
template<bool RELU, bool OUTB, bool EAFILL>
__global__ __launch_bounds__(256) void mgemm_k(
    const u16* __restrict__ A,
    const u16* __restrict__ Bt, const float* __restrict__ bias,
    void* __restrict__ Cv,
    int M, int N, int K, int lda, int ldc,
    const float* __restrict__ ea, long e0)
{
  __shared__ u16 As[64 * 64];
  __shared__ u16 Bs[64 * 64];
  const int tid = threadIdx.x;
  const int brow = blockIdx.y * 64, bcol = blockIdx.x * 64;
  const int wid = tid >> 6, lane = tid & 63;
  const int wr = wid >> 1, wc = wid & 1;
  const int lrow = lane & 15, lk8 = (lane >> 4) * 8;

  f32x4 acc[2][2] = {};

  for (int k0 = 0; k0 < K; k0 += 64) {
#pragma unroll
    for (int s = 0; s < 2; ++s) {
      int c = tid + s * 256;
      int r = c >> 3, kq = (c & 7) * 8;
      const u16* sp = A + (size_t)(brow + r) * lda + k0 + kq;
      short8 v = *(const short8*)sp;
      int byt = (r * 128 + kq * 2) ^ ((r & 7) << 4);
      *(short8*)((char*)As + byt) = v;
    }
#pragma unroll
    for (int s = 0; s < 2; ++s) {
      int c = tid + s * 256;
      int r = c >> 3, kq = (c & 7) * 8;
      const u16* sp = Bt + (size_t)(bcol + r) * K + k0 + kq;
      short8 v = *(const short8*)sp;
      int byt = (r * 128 + kq * 2) ^ ((r & 7) << 4);
      *(short8*)((char*)Bs + byt) = v;
    }
    __syncthreads();
#pragma unroll
    for (int ks = 0; ks < 2; ++ks) {
      short8 a[2], b[2];
#pragma unroll
      for (int m = 0; m < 2; ++m) {
        int r = wr * 32 + m * 16 + lrow;
        int kk = ks * 32 + lk8;
        int byt = (r * 128 + kk * 2) ^ ((r & 7) << 4);
        a[m] = *(const short8*)((const char*)As + byt);
      }
#pragma unroll
      for (int n = 0; n < 2; ++n) {
        int r = wc * 32 + n * 16 + lrow;
        int kk = ks * 32 + lk8;
        int byt = (r * 128 + kk * 2) ^ ((r & 7) << 4);
        b[n] = *(const short8*)((const char*)Bs + byt);
      }
#pragma unroll
      for (int m = 0; m < 2; ++m)
#pragma unroll
        for (int n = 0; n < 2; ++n)
          acc[m][n] = __builtin_amdgcn_mfma_f32_16x16x32_bf16(a[m], b[n], acc[m][n], 0, 0, 0);
    }
    __syncthreads();
  }

#pragma unroll
  for (int m = 0; m < 2; ++m)
#pragma unroll
    for (int n = 0; n < 2; ++n) {
      int col = bcol + wc * 32 + n * 16 + (lane & 15);
      float bv = bias[col];
#pragma unroll
      for (int j = 0; j < 4; ++j) {
        int row = brow + wr * 32 + m * 16 + (lane >> 4) * 4 + j;
        float v = acc[m][n][j] + bv;
        if (RELU) v = fmaxf(v, 0.f);
        if (OUTB) ((u16*)Cv)[(size_t)row * ldc + col] = f2b(v);
        else      ((float*)Cv)[(size_t)row * ldc + col] = v;
      }
    }
  if (EAFILL) {
    for (int i = tid; i < 64 * 64; i += 256) {
      int r = i >> 6, c = i & 63;
      ((u16*)Cv)[(size_t)(brow + r) * 128 + 64 + c] =
          f2b(ea[(size_t)(e0 + brow + r) * 64 + c]);
    }
  }
}

// ---------------------------------------------------------------------------
// bf16 MFMA GEMM, 64x64 tile, z-batched (postW1 over towers; fu2/fv2)
// ---------------------------------------------------------------------------
template<bool RELU, bool OUTB>
__global__ __launch_bounds__(256) void mgemm_z_k(
    const u16* __restrict__ A0,
    const u16* __restrict__ Bt0, const float* __restrict__ bias0,
    void* __restrict__ Cv,
    int M, int N, int K, int lda, int ldc,
    size_t aZ, size_t btZ, size_t bZ, size_t cZ)
{
  __shared__ u16 As[64 * 64];
  __shared__ u16 Bs[64 * 64];
  const int z = blockIdx.z;
  const u16* A = A0 + (size_t)z * aZ;
  const u16* Bt = Bt0 + (size_t)z * btZ;
  const float* bias = bias0 + (size_t)z * bZ;
  const int tid = threadIdx.x;
  const int brow = blockIdx.y * 64, bcol = blockIdx.x * 64;
  const int wid = tid >> 6, lane = tid & 63;
  const int wr = wid >> 1, wc = wid & 1;
  const int lrow = lane & 15, lk8 = (lane >> 4) * 8;

  f32x4 acc[2][2] = {};

  for (int k0 = 0; k0 < K; k0 += 64) {
#pragma unroll
    for (int s = 0; s < 2; ++s) {
      int c = tid + s * 256;
      int r = c >> 3, kq = (c & 7) * 8;
      const u16* sp = A + (size_t)(brow + r) * lda + k0 + kq;
      short8 v = *(const short8*)sp;
      int byt = (r * 128 + kq * 2) ^ ((r & 7) << 4);
      *(short8*)((char*)As + byt) = v;
    }
#pragma unroll
    for (int s = 0; s < 2; ++s) {
      int c = tid + s * 256;
      int r = c >> 3, kq = (c & 7) * 8;
      const u16* sp = Bt + (size_t)(bcol + r) * K + k0 + kq;
      short8 v = *(const short8*)sp;
      int byt = (r * 128 + kq * 2) ^ ((r & 7) << 4);
      *(short8*)((char*)Bs + byt) = v;
    }
    __syncthreads();
#pragma unroll
    for (int ks = 0; ks < 2; ++ks) {
      short8 a[2], b[2];
#pragma unroll
      for (int m = 0; m < 2; ++m) {
        int r = wr * 32 + m * 16 + lrow;
        int kk = ks * 32 + lk8;
        int byt = (r * 128 + kk * 2) ^ ((r & 7) << 4);
        a[m] = *(const short8*)((const char*)As + byt);
      }
#pragma unroll
      for (int n = 0; n < 2; ++n) {
        int r = wc * 32 + n * 16 + lrow;
        int kk = ks * 32 + lk8;
        int byt = (r * 128 + kk * 2) ^ ((r & 7) << 4);
        b[n] = *(const short8*)((const char*)Bs + byt);
      }
#pragma unroll
      for (int m = 0; m < 2; ++m)
#pragma unroll
        for (int n = 0; n < 2; ++n)
          acc[m][n] = __builtin_amdgcn_mfma_f32_16x16x32_bf16(a[m], b[n], acc[m][n], 0, 0, 0);
    }
    __syncthreads();
  }

#pragma unroll
  for (int m = 0; m < 2; ++m)
#pragma unroll
    for (int n = 0; n < 2; ++n) {
      int col = bcol + wc * 32 + n * 16 + (lane & 15);
      float bv = bias[col];
#pragma unroll
      for (int j = 0; j < 4; ++j) {
        int row = brow + wr * 32 + m * 16 + (lane >> 4) * 4 + j;
        float v = acc[m][n][j] + bv;
        if (RELU) v = fmaxf(v, 0.f);
        if (OUTB) ((u16*)Cv + (size_t)z * cZ)[(size_t)row * ldc + col] = f2b(v);
        else      ((float*)Cv + (size_t)z * cZ)[(size_t)row * ldc + col] = v;
      }
    }
}

// ---------------------------------------------------------------------------
// bf16 MFMA GEMM, 128x128 tile. Non-MUL: gl_lds staging (src-granule swizzle).
// MUL: reg-staged A.*A2 with dual gather. M%128==0, N%128==0, K%64==0.
// ---------------------------------------------------------------------------
template<bool RELU, bool GATHER, bool MUL, bool OUTB>
__global__ __launch_bounds__(256) void mg2_k(
    const u16* __restrict__ A, const u16* __restrict__ A2,
    const int* __restrict__ idx, const int* __restrict__ idx2,
    const u16* __restrict__ Bt, const float* __restrict__ bias,
    void* __restrict__ Cv,
    int M, int N, int K, int lda, int ldc)
{
  __shared__ u16 As[128 * 64];
  __shared__ u16 Bs[128 * 64];
  __shared__ int ridx[128];
  __shared__ int ridx2[128];
  const int tid = threadIdx.x;
  const int brow = blockIdx.y * 128, bcol = blockIdx.x * 128;
  const int wid = tid >> 6, lane = tid & 63;
  const int wr = wid >> 1, wc = wid & 1;
  const int lrow = lane & 15, lkg = lane >> 4;

  if (GATHER) {
    if (tid < 128) {
      ridx[tid] = idx[brow + tid];
      if (MUL) ridx2[tid] = idx2[brow + tid];
    }
    __syncthreads();
  }

  f32x4 acc[4][4] = {};

  const char* srcA[4];
  const char* srcB[4];
#pragma unroll
  for (int s = 0; s < 4; ++s) {
    int i = tid + s * 256;
    int r = i >> 3, g = i & 7;
    size_t grow = GATHER ? (size_t)ridx[r] : (size_t)(brow + r);
    int gq = (g ^ (r & 7)) * 8;
    srcA[s] = (const char*)(A + grow * lda + gq);
    srcB[s] = (const char*)(Bt + (size_t)(bcol + r) * K + gq);
  }

  for (int k0 = 0; k0 < K; k0 += 64) {
    if constexpr (!MUL) {
#pragma unroll
      for (int s = 0; s < 4; ++s)
        gl_lds16(srcA[s] + (size_t)k0 * 2, (char*)As + s * 4096 + wid * 1024);
#pragma unroll
      for (int s = 0; s < 4; ++s)
        gl_lds16(srcB[s] + (size_t)k0 * 2, (char*)Bs + s * 4096 + wid * 1024);
    } else {
#pragma unroll
      for (int s = 0; s < 4; ++s) {
        int i = tid + s * 256;
        int r = i >> 3, kq = (i & 7) * 8;
        size_t grow = GATHER ? (size_t)ridx[r] : (size_t)(brow + r);
        size_t grow2 = GATHER ? (size_t)ridx2[r] : (size_t)(brow + r);
        const u16* sp = A + grow * lda + k0 + kq;
        short8 v = *(const short8*)sp;
        const u16* sp2 = A2 + grow2 * lda + k0 + kq;
        short8 v2 = *(const short8*)sp2;
#pragma unroll
        for (int e = 0; e < 8; ++e)
          v[e] = (short)f2b(b2f((u16)v[e]) * b2f((u16)v2[e]));
        int byt = (r * 128 + kq * 2) ^ ((r & 7) << 4);
        *(short8*)((char*)As + byt) = v;
      }
#pragma unroll
      for (int s = 0; s < 4; ++s) {
        int i = tid + s * 256;
        int r = i >> 3, kq = (i & 7) * 8;
        const u16* sp = Bt + (size_t)(bcol + r) * K + k0 + kq;
        short8 v = *(const short8*)sp;
        int byt = (r * 128 + kq * 2) ^ ((r & 7) << 4);
        *(short8*)((char*)Bs + byt) = v;
      }
    }
    __syncthreads();
#pragma unroll
    for (int ks = 0; ks < 2; ++ks) {
      const int kb = ks * 64 + lkg * 16;
      short8 a[4], b[4];
#pragma unroll
      for (int m = 0; m < 4; ++m) {
        int r = wr * 64 + m * 16 + lrow;
        int byt = (r * 128 + kb) ^ ((r & 7) << 4);
        a[m] = *(const short8*)((const char*)As + byt);
      }
#pragma unroll
      for (int n = 0; n < 4; ++n) {
        int r = wc * 64 + n * 16 + lrow;
        int byt = (r * 128 + kb) ^ ((r & 7) << 4);
        b[n] = *(const short8*)((const char*)Bs + byt);
      }
#pragma unroll
      for (int m = 0; m < 4; ++m)
#pragma unroll
        for (int n = 0; n < 4; ++n)
          acc[m][n] = __builtin_amdgcn_mfma_f32_16x16x32_bf16(a[m], b[n], acc[m][n], 0, 0, 0);
    }
    __syncthreads();
  }

#pragma unroll
  for (int m = 0; m < 4; ++m)
#pragma unroll
    for (int n = 0; n < 4; ++n) {
      int col = bcol + wc * 64 + n * 16 + lrow;
      float bv = bias[col];
#pragma unroll
      for (int j = 0; j < 4; ++j) {
        int row = brow + wr * 64 + m * 16 + lkg * 4 + j;
        float v = acc[m][n][j] + bv;
        if (RELU) v = fmaxf(v, 0.f);
        if (OUTB) ((u16*)Cv)[(size_t)row * ldc + col] = f2b(v);
        else      ((float*)Cv)[(size_t)row * ldc + col] = v;
      }
    }
}

// ===========================================================================
// CONVF: fused conv message path per (128-edge tile, tower):
//  phase1: EAH = ea[eidx]@EW_t + bc_t -> H (bf16, swizzled)
//  vector pass: H += XI_t[dst] + XJ_t[src]; relu   (short8 on swizzled H)
//  phase2: msg = h @ W2_t + b2_t (K=128, full 4 k-steps) -> H
//  merge:  dst-sorted segmented reduce -> atomic sum/sumsq/max
// grid (Mc/128, T), XCD-swizzled blockIdx.x.
// ===========================================================================
__global__ __launch_bounds__(256) void convf_k(
    const u16* __restrict__ eab, const int* __restrict__ eidx,
    const int* __restrict__ src, const int* __restrict__ dst, long base,
    const u16* __restrict__ EWt, const float* __restrict__ bc,
    const u16* __restrict__ XIJ,
    const u16* __restrict__ W2t, const float* __restrict__ b2,
    float* __restrict__ sumb, float* __restrict__ sumsqb,
    unsigned* __restrict__ mxb, int Nn)
{
  __shared__ u16 AB[128 * 128];   // 32KB
  __shared__ u16 H[128 * 128];    // 32KB
  __shared__ int nid[128], sidm[128];
  u16* As = AB;
  u16* Bs = AB + 128 * 64;
  const int tid = threadIdx.x;
  const int brow = xcd_swz(blockIdx.x, gridDim.x) * 128;
  const int t = blockIdx.y;
  const int wid = tid >> 6, lane = tid & 63;
  const int wr = wid >> 1, wc = wid & 1;
  const int lrow = lane & 15, lkg = lane >> 4;

  __shared__ int eids[128];
  if (tid < 128) {
    int e = eidx[base + brow + tid];
    eids[tid] = e;
    nid[tid] = dst[e];
    sidm[tid] = src[e];
  }
  __syncthreads();

  // phase1 staging: eab tile (gathered rows, K=64) + EW_t tile
#pragma unroll
  for (int s = 0; s < 4; ++s) {
    int i = tid + s * 256;
    int r = i >> 3, g = i & 7;
    int gq = (g ^ (r & 7)) * 8;
    gl_lds16(eab + (size_t)eids[r] * 64 + gq, (char*)As + s * 4096 + wid * 1024);
  }
#pragma unroll
  for (int s = 0; s < 4; ++s) {
    int i = tid + s * 256;
    int r = i >> 3, g = i & 7;
    int gq = (g ^ (r & 7)) * 8;
    gl_lds16(EWt + (size_t)(t * 128 + r) * 64 + gq, (char*)Bs + s * 4096 + wid * 1024);
  }
  __syncthreads();

  f32x4 acc[4][4] = {};
#pragma unroll
  for (int ks = 0; ks < 2; ++ks) {
    const int kb = ks * 64 + lkg * 16;
    short8 a[4], b[4];
#pragma unroll
    for (int m = 0; m < 4; ++m) {
      int r = wr * 64 + m * 16 + lrow;
      int byt = (r * 128 + kb) ^ ((r & 7) << 4);
      a[m] = *(const short8*)((const char*)As + byt);
    }
#pragma unroll
    for (int n = 0; n < 4; ++n) {
      int r = wc * 64 + n * 16 + lrow;
      int byt = (r * 128 + kb) ^ ((r & 7) << 4);
      b[n] = *(const short8*)((const char*)Bs + byt);
    }
#pragma unroll
    for (int m = 0; m < 4; ++m)
#pragma unroll
      for (int n = 0; n < 4; ++n)
        acc[m][n] = __builtin_amdgcn_mfma_f32_16x16x32_bf16(a[m], b[n], acc[m][n], 0, 0, 0);
  }

  // epilogue: EAH + bias -> H (swizzled, 256B rows), NO XIJ yet
#pragma unroll
  for (int m = 0; m < 4; ++m)
#pragma unroll
    for (int n = 0; n < 4; ++n) {
      int cl = wc * 64 + n * 16 + lrow;
      float bv = bc[t * 128 + cl];
#pragma unroll
      for (int j = 0; j < 4; ++j) {
        int rl = wr * 64 + m * 16 + lkg * 4 + j;
        int byt = (rl * 256 + cl * 2) ^ ((rl & 7) << 4);
        *(u16*)((char*)H + byt) = f2b(acc[m][n][j] + bv);
      }
    }
  __syncthreads();   // H writes visible; As/Bs reads done -> AB free

  // issue W2 staging EARLY (latency hides under the XIJ vector pass)
#pragma unroll
  for (int s = 0; s < 8; ++s) {
    int i = tid + s * 256;
    int r = i >> 4, g = i & 15;
    int gs = (g & 8) | ((g & 7) ^ (r & 7));
    gl_lds16(W2t + (size_t)t * 16384 + (size_t)r * 128 + gs * 8,
             (char*)AB + s * 4096 + wid * 1024);
  }

  // vector XIJ pass: h = relu(EAH + XI[dst] + XJ[src]), short8 on swizzled H
#pragma unroll
  for (int s = 0; s < 8; ++s) {
    int i = tid + s * 256;             // 0..2047
    int row = i >> 4, q = i & 15;      // q*8 = col0
    int byt = (row * 256 + q * 16) ^ ((row & 7) << 4);
    short8 h8 = *(const short8*)((const char*)H + byt);
    short8 a8 = *(const short8*)(XIJ + (size_t)nid[row] * 1024 + t * 128 + q * 8);
    short8 c8 = *(const short8*)(XIJ + (size_t)sidm[row] * 1024 + 512 + t * 128 + q * 8);
#pragma unroll
    for (int e = 0; e < 8; ++e) {
      float v = b2f((u16)h8[e]) + b2f((u16)a8[e]) + b2f((u16)c8[e]);
      h8[e] = (short)f2b(fmaxf(v, 0.f));
    }
    *(short8*)((char*)H + byt) = h8;
  }
  __syncthreads();   // waits W2 staging (vmcnt) + H updates

  // phase2: msg = H @ W2s^T, K=128, FULL 4 k-steps
  f32x4 acc2[4][4] = {};
#pragma unroll
  for (int ks = 0; ks < 4; ++ks) {
    const int kb = ks * 64 + lkg * 16;
    short8 a[4], b[4];
#pragma unroll
    for (int m = 0; m < 4; ++m) {
      int r = wr * 64 + m * 16 + lrow;
      int byt = (r * 256 + kb) ^ ((r & 7) << 4);
      a[m] = *(const short8*)((const char*)H + byt);
    }
#pragma unroll
    for (int n = 0; n < 4; ++n) {
      int c = wc * 64 + n * 16 + lrow;
      int byt = (c * 256 + kb) ^ ((c & 7) << 4);
      b[n] = *(const short8*)((const char*)AB + byt);
    }
#pragma unroll
    for (int m = 0; m < 4; ++m)
#pragma unroll
      for (int n = 0; n < 4; ++n)
        acc2[m][n] = __builtin_amdgcn_mfma_f32_16x16x32_bf16(a[m], b[n], acc2[m][n], 0, 0, 0);
  }
  __syncthreads();   // H reads done

  // msg -> H (swizzled; merge read uses same XOR)
#pragma unroll
  for (int m = 0; m < 4; ++m)
#pragma unroll
    for (int n = 0; n < 4; ++n) {
      int col = wc * 64 + n * 16 + lrow;
      float bv = b2[t * 128 + col];
#pragma unroll
      for (int j = 0; j < 4; ++j) {
        int row = wr * 64 + m * 16 + lkg * 4 + j;
        int byt = (row * 256 + col * 2) ^ ((row & 7) << 4);
        *(u16*)((char*)H + byt) = f2b(acc2[m][n][j] + bv);
      }
    }
  __syncthreads();

  // segmented merge: 256 thr = (col 0..127) x (half 0..1)
  {
    const int col = tid & 127, half = tid >> 7;
    const int r0 = half * 64;
    float* sb = sumb + (size_t)t * Nn * 128;
    float* qb = sumsqb + (size_t)t * Nn * 128;
    unsigned* xbp = mxb + (size_t)t * Nn * 128;
    int cur = nid[r0];
    float sacc = 0.f, qacc = 0.f, mxv = -INFINITY;
    for (int rr = 0; rr < 64; ++rr) {
      int row = r0 + rr;
      int nd = nid[row];
      if (nd != cur) {
        size_t o = (size_t)cur * 128 + col;
        atomicAdd(&sb[o], sacc);
        atomicAdd(&qb[o], qacc);
        unsigned ub = __float_as_uint(mxv);
        atomicMax(&xbp[o], (ub & 0x80000000u) ? ~ub : (ub | 0x80000000u));
        cur = nd; sacc = 0.f; qacc = 0.f; mxv = -INFINITY;
      }
      int byt = (row * 256 + col * 2) ^ ((row & 7) << 4);
      float v = b2f(*(const u16*)((const char*)H + byt));
      sacc += v; qacc += v * v; mxv = fmaxf(mxv, v);
    }
    size_t o = (size_t)cur * 128 + col;
    atomicAdd(&sb[o], sacc);
    atomicAdd(&qb[o], qacc);
    unsigned ub = __float_as_uint(mxv);
    atomicMax(&xbp[o], (ub & 0x80000000u) ? ~ub : (ub | 0x80000000u));
  }
}

// ===========================================================================
// EU fused: eu1 = relu(ecat@euW1^T + b1) (128x128, in LDS), then
// ea = eu1@euW2^T + b2 -> EAp (fp32) + eab (bf16). grid (Mc/128).
// ===========================================================================
__global__ __launch_bounds__(256) void eu_fused_k(
    const u16* __restrict__ C3b,
    const u16* __restrict__ euW1t, const float* __restrict__ eu_b1,
    const u16* __restrict__ euW2t, const float* __restrict__ eu_b2,
    float* __restrict__ EAp, u16* __restrict__ eab, long e0)
{
  __shared__ u16 SM[128 * 128];
  __shared__ u16 W2s[64 * 128];
  u16* As = SM;
  u16* Bs = SM + 128 * 64;
  const int tid = threadIdx.x;
  const int brow = blockIdx.x * 128;
  const int wid = tid >> 6, lane = tid & 63;
  const int wr = wid >> 1, wc = wid & 1;
  const int lrow = lane & 15, lkg = lane >> 4;

#pragma unroll
  for (int s = 0; s < 4; ++s) {
    int i = tid + s * 256;
    int r = i >> 4, g = i & 15;
    int gs = (g & 8) | ((g & 7) ^ (r & 7));
    gl_lds16(euW2t + (size_t)r * 128 + gs * 8, (char*)W2s + s * 4096 + wid * 1024);
  }

  const char* srcA[4];
  const char* srcB[4];
#pragma unroll
  for (int s = 0; s < 4; ++s) {
    int i = tid + s * 256;
    int r = i >> 3, g = i & 7;
    int gq = (g ^ (r & 7)) * 8;
    srcA[s] = (const char*)(C3b + (size_t)(brow + r) * 128 + gq);
    srcB[s] = (const char*)(euW1t + (size_t)r * 128 + gq);
  }

  f32x4 acc[4][4] = {};
  for (int k0 = 0; k0 < 128; k0 += 64) {
#pragma unroll
    for (int s = 0; s < 4; ++s)
      gl_lds16(srcA[s] + (size_t)k0 * 2, (char*)As + s * 4096 + wid * 1024);
#pragma unroll
    for (int s = 0; s < 4; ++s)
      gl_lds16(srcB[s] + (size_t)k0 * 2, (char*)Bs + s * 4096 + wid * 1024);
    __syncthreads();
#pragma unroll
    for (int ks = 0; ks < 2; ++ks) {
      const int kb = ks * 64 + lkg * 16;
      short8 a[4], b[4];
#pragma unroll
      for (int m = 0; m < 4; ++m) {
        int r = wr * 64 + m * 16 + lrow;
        int byt = (r * 128 + kb) ^ ((r & 7) << 4);
        a[m] = *(const short8*)((const char*)As + byt);
      }
#pragma unroll
      for (int n = 0; n < 4; ++n) {
        int r = wc * 64 + n * 16 + lrow;
        int byt = (r * 128 + kb) ^ ((r & 7) << 4);
        b[n] = *(const short8*)((const char*)Bs + byt);
      }
#pragma unroll
      for (int m = 0; m < 4; ++m)
#pragma unroll
        for (int n = 0; n < 4; ++n)
          acc[m][n] = __builtin_amdgcn_mfma_f32_16x16x32_bf16(a[m], b[n], acc[m][n], 0, 0, 0);
    }
    __syncthreads();
  }

#pragma unroll
  for (int m = 0; m < 4; ++m)
#pragma unroll
    for (int n = 0; n < 4; ++n) {
      int col = wc * 64 + n * 16 + lrow;
      float bv = eu_b1[col];
#pragma unroll
      for (int j = 0; j < 4; ++j) {
        int row = wr * 64 + m * 16 + lkg * 4 + j;
        float v = fmaxf(acc[m][n][j] + bv, 0.f);
        int byt = (row * 256 + col * 2) ^ ((row & 7) << 4);
        *(u16*)((char*)SM + byt) = f2b(v);
      }
    }
  __syncthreads();

  f32x4 acc2[2][4] = {};
#pragma unroll
  for (int ks = 0; ks < 4; ++ks) {
    const int kb = ks * 64 + lkg * 16;
    short8 a[2], b[4];
#pragma unroll
    for (int m = 0; m < 2; ++m) {
      int r = wid * 32 + m * 16 + lrow;
      int byt = (r * 256 + kb) ^ ((r & 7) << 4);
      a[m] = *(const short8*)((const char*)SM + byt);
    }
#pragma unroll
    for (int n = 0; n < 4; ++n) {
      int c = n * 16 + lrow;
      int byt = (c * 256 + kb) ^ ((c & 7) << 4);
      b[n] = *(const short8*)((const char*)W2s + byt);
    }
#pragma unroll
    for (int m = 0; m < 2; ++m)
#pragma unroll
      for (int n = 0; n < 4; ++n)
        acc2[m][n] = __builtin_amdgcn_mfma_f32_16x16x32_bf16(a[m], b[n], acc2[m][n], 0, 0, 0);
  }

#pragma unroll
  for (int m = 0; m < 2; ++m)
#pragma unroll
    for (int n = 0; n < 4; ++n) {
      int col = n * 16 + lrow;
      float bv = eu_b2[col];
#pragma unroll
      for (int j = 0; j < 4; ++j) {
        int row = wid * 32 + m * 16 + lkg * 4 + j;
        float v = acc2[m][n][j] + bv;
        size_t o = (size_t)(e0 + brow + row) * 64 + col;
        EAp[o] = v;
        eab[o] = f2b(v);
      }
    }
}

// ---------------------------------------------------------------------------
// Edge sort by dst (counting sort, shuffle scan)
// ---------------------------------------------------------------------------
__global__ void deg_kernel(const int* __restrict__ dst, int* __restrict__ deg, int E)
{
  int e = blockIdx.x * blockDim.x + threadIdx.x;
  if (e < E) atomicAdd(&deg[dst[e]], 1);
}

__global__ void scan_kernel(const int* __restrict__ deg, int* __restrict__ rowptr, int n)
{
  __shared__ int wsum[4];
  __shared__ int carry_s;
  const int tid = threadIdx.x, lane = tid & 63, wv = tid >> 6;
  if (tid == 0) carry_s = 0;
  __syncthreads();
  for (int base = 0; base < n; base += 256) {
    int i = base + tid;
    int v = (i < n) ? deg[i] : 0;
    int s = v;
#pragma unroll
    for (int off = 1; off < 64; off <<= 1) {
      int t = __shfl_up(s, off, 64);
      if (lane >= off) s += t;
    }
    if (lane == 63) wsum[wv] = s;
    __syncthreads();
    int wo = carry_s;
    for (int q = 0; q < wv; ++q) wo += wsum[q];
    int tot = carry_s + wsum[0] + wsum[1] + wsum[2] + wsum[3];
    __syncthreads();
    if (i < n) rowptr[i] = wo + s - v;
    if (tid == 0) carry_s = tot;
    __syncthreads();
  }
  if (threadIdx.x == 0) rowptr[n] = carry_s;
}

__global__ void scatter_kernel(const int* __restrict__ dst, int* __restrict__ cursor,
                               int* __restrict__ eidx, int E)
{
  int e = blockIdx.x * blockDim.x + threadIdx.x;
  if (e < E) {
    int p = atomicAdd(&cursor[dst[e]], 1);
    eidx[p] = e;
  }
}

// ---------------------------------------------------------------------------
// Weight prep
// ---------------------------------------------------------------------------
__global__ void wtb_kernel(const float* __restrict__ W, u16* __restrict__ Wt,
                           int K, int N, size_t wtStride)
{
  int b = blockIdx.y;
  const float* Wb = W + (size_t)b * K * N;
  u16* Wtb = Wt + (size_t)b * wtStride;
  for (int i = blockIdx.x * blockDim.x + threadIdx.x; i < K * N;
       i += gridDim.x * blockDim.x) {
    int k = i / N, n = i % N;
    Wtb[(size_t)n * K + k] = f2b(Wb[i]);
  }
}

__global__ void wtbsub_kernel(const float* __restrict__ W, u16* __restrict__ Wt,
                              int k0, size_t lStride)
{
  int b = blockIdx.y;
  int l = b >> 2, t = b & 3;
  const float* Wb = W + (size_t)b * 384 * 128 + (size_t)k0 * 128;
  u16* Wtb = Wt + (size_t)l * lStride + (size_t)t * 16384;
  for (int i = blockIdx.x * blockDim.x + threadIdx.x; i < 16384;
       i += gridDim.x * blockDim.x) {
    int n = i >> 7, k = i & 127;
    Wtb[(size_t)n * 128 + k] = f2b(Wb[(size_t)k * 128 + n]);
  }
}

__global__ void ewcomb_kernel(const float* __restrict__ encW,
                              const float* __restrict__ preW1, u16* __restrict__ EWt)
{
  int i = blockIdx.x * blockDim.x + threadIdx.x;
  if (i >= GL * 512 * 64) return;
  int l = i / (512 * 64);
  int rem = i % (512 * 64);
  int n = rem / 64, k = rem % 64;
  int t = n >> 7, o = n & 127;
  const float* eW = encW + (size_t)l * 64 * 128 + (size_t)k * 128;
  const float* pW = preW1 + ((size_t)(l * GT + t) * 384 + 256) * 128 + o;
  float s = 0.f;
  for (int j = 0; j < 128; ++j) s += eW[j] * pW[(size_t)j * 128];
  EWt[i] = f2b(s);
}

__global__ void bcomb_kernel(const float* __restrict__ encb,
                             const float* __restrict__ preb1,
                             const float* __restrict__ preW1, float* __restrict__ bc)
{
  int i = blockIdx.x * blockDim.x + threadIdx.x;
  if (i >= GL * 512) return;
  int l = i / 512, n = i % 512;
  int t = n >> 7, o = n & 127;
  const float* eb = encb + (size_t)l * 128;
  const float* pW = preW1 + ((size_t)(l * GT + t) * 384 + 256) * 128 + o;
  float s = preb1[(size_t)(l * GT + t) * 128 + o];
  for (int j = 0; j < 128; ++j) s += eb[j] * pW[(size_t)j * 128];
  bc[i] = s;
}

__global__ void biaspad_kernel(const float* __restrict__ b32, float* __restrict__ b64, int total)
{
  int i = blockIdx.x * blockDim.x + threadIdx.x;
  if (i >= total) return;
  b64[(i / 32) * 64 + (i % 32)] = b32[i];
}

__global__ void f2b_kernel(const float* __restrict__ in, u16* __restrict__ out, int n)
{
  int i = blockIdx.x * blockDim.x + threadIdx.x;
  if (i < n) out[i] = f2b(in[i]);
}

// ---------------------------------------------------------------------------
// Aggregator init
// ---------------------------------------------------------------------------
__global__ void agg_init_kernel(float* __restrict__ s, float* __restrict__ ss,
                                unsigned* __restrict__ mx, int total)
{
  int i = blockIdx.x * blockDim.x + threadIdx.x;
  if (i >= total) return;
  s[i] = 0.f; ss[i] = 0.f; mx[i] = 0x007FFFFFu;
}

// ---------------------------------------------------------------------------
// Finalize ALL towers -> catb4 bf16
// ---------------------------------------------------------------------------
__global__ void finalize_kernel(
    const float* __restrict__ sumb, const float* __restrict__ sumsqb,
    const unsigned* __restrict__ mxb, const int* __restrict__ rowptr,
    const float* __restrict__ x, u16* __restrict__ catb4, int Nn)
{
  int i = blockIdx.x * blockDim.x + threadIdx.x;
  if (i >= 4 * Nn * 128) return;
  int t = i / (Nn * 128);
  int j = i - t * Nn * 128;
  int n = j >> 7, c = j & 127;
  float cnt = fmaxf((float)(rowptr[n + 1] - rowptr[n]), 1.f);
  float mean = sumb[i] / cnt;
  float msq  = sumsqb[i] / cnt;
  float sd = sqrtf(fmaxf(msq - mean * mean, 0.f) + 1e-5f);
  unsigned u = mxb[i];
  unsigned bits = (u & 0x80000000u) ? (u & 0x7FFFFFFFu) : ~u;
  float mxv = __uint_as_float(bits);
  if ((bits & 0x7F800000u) == 0x7F800000u) mxv = 0.f;
  u16* cb = catb4 + ((size_t)t * GNP + n) * 512;
  cb[c]       = f2b(x[(size_t)n * 128 + c]);
  cb[128 + c] = f2b(mean);
  cb[256 + c] = f2b(mxv);
  cb[384 + c] = f2b(sd);
}

// ---------------------------------------------------------------------------
// GRU elementwise combine (+ bf16 copy of new h)
// ---------------------------------------------------------------------------
__global__ void gru_kernel(const float* __restrict__ gi, const float* __restrict__ gh,
                           const float* __restrict__ h, float* __restrict__ hout,
                           u16* __restrict__ xbo, int total)
{
  int i = blockIdx.x * blockDim.x + threadIdx.x;
  if (i >= total) return;
  int n = i >> 7, c = i & 127;
  const float* gin = gi + (size_t)n * 384;
  const float* ghn = gh + (size_t)n * 384;
  float ir = gin[c], iz = gin[128 + c], inn = gin[256 + c];
  float hr = ghn[c], hz = ghn[128 + c], hn = ghn[256 + c];
  float r = 1.f / (1.f + __expf(-(ir + hr)));
  float z = 1.f / (1.f + __expf(-(iz + hz)));
  float nn = tanhf(inn + r * hn);
  float v = (1.f - z) * nn + z * h[i];
  hout[i] = v;
  xbo[i] = f2b(v);
}

// ---------------------------------------------------------------------------
extern "C" void kernel_launch(void* const* d_in, const int* in_sizes, int n_in,
                              void* d_out, int out_size, void* d_ws, size_t ws_size,
                              hipStream_t stream)
{
  const int N_ = GN, E_ = GE, Np = GNP;

  const float* x_in   = (const float*)d_in[0];
  const int*   src    = (const int*)d_in[1];
  const int*   dst    = src + E_;
  const float* ea_in  = (const float*)d_in[2];
  const float* enc_W  = (const float*)d_in[3];
  const float* enc_b  = (const float*)d_in[4];
  const float* pre_W1 = (const float*)d_in[5];
  const float* pre_b1 = (const float*)d_in[6];
  const float* pre_W2 = (const float*)d_in[7];
  const float* pre_b2 = (const float*)d_in[8];
  const float* post_W1 = (const float*)d_in[9];
  const float* post_b1 = (const float*)d_in[10];
  const float* post_W2 = (const float*)d_in[11];
  const float* post_b2 = (const float*)d_in[12];
  const float* lin_W  = (const float*)d_in[13];
  const float* lin_b  = (const float*)d_in[14];
  const float* gru_Wi = (const float*)d_in[15];
  const float* gru_Wh = (const float*)d_in[16];
  const float* gru_bi = (const float*)d_in[17];
  const float* gru_bh = (const float*)d_in[18];
  const float* fcu_W1 = (const float*)d_in[19];
  const float* fcu_b1 = (const float*)d_in[20];
  const float* fcu_W2 = (const float*)d_in[21];
  const float* fcu_b2 = (const float*)d_in[22];
  const float* fcv_W1 = (const float*)d_in[23];
  const float* fcv_b1 = (const float*)d_in[24];
  const float* fcv_W2 = (const float*)d_in[25];
  const float* fcv_b2 = (const float*)d_in[26];
  const float* fc_W1  = (const float*)d_in[27];
  const float* fc_b1  = (const float*)d_in[28];
  const float* fc_W2  = (const float*)d_in[29];
  const float* fc_b2  = (const float*)d_in[30];
  const float* eu_W1  = (const float*)d_in[31];
  const float* eu_b1  = (const float*)d_in[32];
  const float* eu_W2  = (const float*)d_in[33];
  const float* eu_b2  = (const float*)d_in[34];

  // ---- workspace arena ----
  size_t used = 0;
  char* w = (char*)d_ws;
  auto alloc = [&](size_t bytes) {
    char* p = w + used;
    used += (bytes + 255) & ~(size_t)255;
    return p;
  };
  float*    sumb   = (float*)alloc((size_t)N_ * 512 * 4);
  float*    sumsqb = (float*)alloc((size_t)N_ * 512 * 4);
  unsigned* mxb    = (unsigned*)alloc((size_t)N_ * 512 * 4);
  float*    q1   = (float*)alloc((size_t)Np * 256 * 4);
  u16*      q2b  = (u16*)alloc((size_t)Np * 128 * 2);
  u16*      mbb  = (u16*)alloc((size_t)Np * 128 * 2);
  float*    gib  = (float*)alloc((size_t)Np * 384 * 4);
  float*    ghb  = (float*)alloc((size_t)Np * 384 * 4);
  float*    Hb   = (float*)alloc((size_t)N_ * 128 * 4);
  u16*      xb   = (u16*)alloc((size_t)Np * 128 * 2);
  u16*      catb4 = (u16*)alloc((size_t)4 * Np * 512 * 2);
  u16*      eab  = (u16*)alloc((size_t)E_ * 64 * 2);
  u16*      XIJ  = (u16*)alloc((size_t)Np * 1024 * 2);
  u16*      FUV1b = (u16*)alloc((size_t)Np * 512 * 2);
  u16*      FUVb  = (u16*)alloc((size_t)Np * 512 * 2);
  float*    zb   = (float*)alloc(1024 * 4);
  // weights
  u16* WIJt   = (u16*)alloc((size_t)GL * 1024 * 128 * 2);
  u16* EWt    = (u16*)alloc((size_t)GL * 512 * 64 * 2);
  float* bcomb = (float*)alloc((size_t)GL * 512 * 4);
  u16* preW2t = (u16*)alloc((size_t)GL * GT * 128 * 128 * 2);
  u16* postW1t = (u16*)alloc((size_t)GL * GT * 64 * 512 * 2);
  float* postb1p = (float*)alloc((size_t)GL * GT * 64 * 4);
  u16* linWt  = (u16*)alloc((size_t)GL * 128 * 128 * 2);
  u16* gruWit = (u16*)alloc((size_t)384 * 128 * 2);
  u16* gruWht = (u16*)alloc((size_t)384 * 128 * 2);
  u16* fuvW1t = (u16*)alloc((size_t)512 * 128 * 2);
  u16* fcuW2t = (u16*)alloc((size_t)256 * 256 * 2);
  u16* fcvW2t = (u16*)alloc((size_t)256 * 256 * 2);
  float* fuvb1 = (float*)alloc(512 * 4);
  float* fuvb2 = (float*)alloc(512 * 4);
  u16* fcW1t  = (u16*)alloc((size_t)256 * 256 * 2);
  u16* fcW2t  = (u16*)alloc((size_t)64 * 256 * 2);
  u16* euW1t  = (u16*)alloc((size_t)128 * 128 * 2);
  u16* euW2t  = (u16*)alloc((size_t)64 * 128 * 2);
  int* eidx   = (int*)alloc((size_t)E_ * 4);
  int* degb   = (int*)alloc((size_t)(N_ + 1) * 4);
  int* rowptr = (int*)alloc((size_t)(N_ + 1) * 4);
  int* cursor = (int*)alloc((size_t)(N_ + 1) * 4);

  // chunk arena: 768 B/row (edge chain only: C1b 512B + C3b 256B)
  size_t avail = (ws_size > used + 4096) ? (ws_size - used - 4096) : 0;
  long Ec = (long)(avail / 768);
  if (Ec > E_) Ec = E_;
  Ec &= ~255L;
  if (Ec < 256) return;   // ws too small: fail cleanly
  char* arena = alloc((size_t)Ec * 768);
  if (used > ws_size) return;
  const int nchunks = (int)((E_ + Ec - 1) / Ec);
  u16* C1b = (u16*)arena;                          // Ec x 256 bf16
  u16* C3b = (u16*)(arena + (size_t)Ec * 512);     // Ec x 128 bf16

  float* out = (float*)d_out;
  float* EAp = out + (size_t)N_ * 128;   // ea state lives in d_out

  // ---- one-time setup ----
  hipMemsetAsync(degb, 0, (size_t)N_ * 4, stream);
  deg_kernel<<<(E_ + 255) / 256, 256, 0, stream>>>(dst, degb, E_);
  scan_kernel<<<1, 256, 0, stream>>>(degb, rowptr, N_);
  hipMemcpyAsync(cursor, rowptr, (size_t)N_ * 4, hipMemcpyDeviceToDevice, stream);
  scatter_kernel<<<(E_ + 255) / 256, 256, 0, stream>>>(dst, cursor, eidx, E_);

  hipMemsetAsync(postW1t, 0, (size_t)GL * GT * 64 * 512 * 2, stream);
  hipMemsetAsync(postb1p, 0, (size_t)GL * GT * 64 * 4, stream);
  hipMemsetAsync(zb, 0, 1024 * 4, stream);
  {
    dim3 gb(48, GL);
    wtb_kernel<<<gb, 256, 0, stream>>>(lin_W, linWt, 128, 128, 128 * 128);
    dim3 gt(48, GL * GT);
    wtb_kernel<<<gt, 256, 0, stream>>>(pre_W2, preW2t, 128, 128, 128 * 128);
    wtb_kernel<<<gt, 256, 0, stream>>>(post_W1, postW1t, 512, 32, 64 * 512);
    dim3 gs(16, GL * GT);
    wtbsub_kernel<<<gs, 256, 0, stream>>>(pre_W1, WIJt, 0, 131072);
    wtbsub_kernel<<<gs, 256, 0, stream>>>(pre_W1, WIJt + 65536, 128, 131072);
    ewcomb_kernel<<<(GL * 512 * 64 + 255) / 256, 256, 0, stream>>>(enc_W, pre_W1, EWt);
    bcomb_kernel<<<(GL * 512 + 255) / 256, 256, 0, stream>>>(enc_b, pre_b1, pre_W1, bcomb);
    dim3 g1(48, 1);
    wtb_kernel<<<g1, 256, 0, stream>>>(gru_Wi, gruWit, 128, 384, 384 * 128);
    wtb_kernel<<<g1, 256, 0, stream>>>(gru_Wh, gruWht, 128, 384, 384 * 128);
    wtb_kernel<<<g1, 256, 0, stream>>>(fcu_W1, fuvW1t, 128, 256, 0);
    wtb_kernel<<<g1, 256, 0, stream>>>(fcv_W1, fuvW1t + 256 * 128, 128, 256, 0);
    wtb_kernel<<<g1, 256, 0, stream>>>(fcu_W2, fcuW2t, 256, 256, 0);
    wtb_kernel<<<g1, 256, 0, stream>>>(fcv_W2, fcvW2t, 256, 256, 0);
    wtb_kernel<<<g1, 256, 0, stream>>>(fc_W1, fcW1t, 256, 256, 0);
    wtb_kernel<<<g1, 256, 0, stream>>>(fc_W2, fcW2t, 256, 64, 0);
    wtb_kernel<<<g1, 256, 0, stream>>>(eu_W1, euW1t, 128, 128, 0);
    wtb_kernel<<<g1, 256, 0, stream>>>(eu_W2, euW2t, 128, 64, 0);
  }
  biaspad_kernel<<<(GL * GT * 32 + 255) / 256, 256, 0, stream>>>(
      post_b1, postb1p, GL * GT * 32);
  hipMemcpyAsync(fuvb1, fcu_b1, 256 * 4, hipMemcpyDeviceToDevice, stream);
  hipMemcpyAsync(fuvb1 + 256, fcv_b1, 256 * 4, hipMemcpyDeviceToDevice, stream);
  hipMemcpyAsync(fuvb2, fcu_b2, 256 * 4, hipMemcpyDeviceToDevice, stream);
  hipMemcpyAsync(fuvb2 + 256, fcv_b2, 256 * 4, hipMemcpyDeviceToDevice, stream);

  f2b_kernel<<<(N_ * 128 + 255) / 256, 256, 0, stream>>>(x_in, xb, N_ * 128);
  f2b_kernel<<<(E_ * 64 + 255) / 256, 256, 0, stream>>>(ea_in, eab, E_ * 64);

  const float* x_cur = x_in;
  const float* ea_cur = ea_in;

  for (int l = 0; l < GL; ++l) {
    // ---- PNA conv ----
    agg_init_kernel<<<(N_ * 512 + 255) / 256, 256, 0, stream>>>(sumb, sumsqb, mxb, N_ * 512);
    {
      dim3 gX(8, Np / 128);
      mg2_k<false, false, false, true><<<gX, 256, 0, stream>>>(
          xb, nullptr, nullptr, nullptr, WIJt + (size_t)l * 131072, zb,
          XIJ, Np, 1024, 128, 128, 1024);
    }
    {
      dim3 gC(E_ / 128, GT);
      convf_k<<<gC, 256, 0, stream>>>(
          eab, eidx, src, dst, 0,
          EWt + (size_t)l * 512 * 64, bcomb + (size_t)l * 512, XIJ,
          preW2t + (size_t)l * GT * 16384, pre_b2 + (size_t)l * 512,
          sumb, sumsqb, mxb, N_);
    }
    finalize_kernel<<<(4 * N_ * 128 + 255) / 256, 256, 0, stream>>>(
        sumb, sumsqb, mxb, rowptr, x_cur, catb4, N_);
    {
      dim3 gP1(1, Np / 64, 4);
      mgemm_z_k<true, false><<<gP1, 256, 0, stream>>>(
          catb4, postW1t + (size_t)l * GT * 64 * 512, postb1p + (size_t)l * GT * 64,
          q1, Np, 64, 512, 512, 64,
          (size_t)Np * 512, (size_t)64 * 512, 64, (size_t)Np * 64);
      dim3 gP2(1, (N_ + 63) / 64, 4);
      gemmz_k<<<gP2, 256, 0, stream>>>(
          q1, post_W2 + (size_t)l * GT * 32 * 32, post_b2 + (size_t)l * GT * 32,
          q2b, N_, 32, 32, 64, 32, 128,
          (size_t)Np * 64, (size_t)32 * 32, 32, 32);
    }
    {
      dim3 gL(1, Np / 128), gG(3, Np / 128);
      mg2_k<false, false, false, true><<<gL, 256, 0, stream>>>(
          q2b, nullptr, nullptr, nullptr, linWt + (size_t)l * 128 * 128,
          lin_b + (size_t)l * 128, mbb, Np, 128, 128, 128, 128);
      mg2_k<false, false, false, false><<<gG, 256, 0, stream>>>(
          mbb, nullptr, nullptr, nullptr, gruWit, gru_bi, gib, Np, 384, 128, 128, 384);
      mg2_k<false, false, false, false><<<gG, 256, 0, stream>>>(
          xb, nullptr, nullptr, nullptr, gruWht, gru_bh, ghb, Np, 384, 128, 128, 384);
    }
    gru_kernel<<<(N_ * 128 + 255) / 256, 256, 0, stream>>>(
        gib, ghb, x_cur, Hb, xb, N_ * 128);

    // ---- edge update: node-level FU/FV, lean per-edge chain ----
    {
      dim3 gF1(4, Np / 128);
      mg2_k<true, false, false, true><<<gF1, 256, 0, stream>>>(
          xb, nullptr, nullptr, nullptr, fuvW1t, fuvb1, FUV1b, Np, 512, 128, 128, 512);
      dim3 gF2(4, Np / 64, 2);
      mgemm_z_k<true, true><<<gF2, 256, 0, stream>>>(
          FUV1b, fcuW2t, fuvb2, FUVb, Np, 256, 256, 512, 256,
          (size_t)256, (size_t)256 * 256, 256, (size_t)Np * 256);
    }
    const u16* FUb = FUVb;
    const u16* FVb = FUVb + (size_t)Np * 256;
    for (int c = 0; c < nchunks; ++c) {
      long e0 = (long)c * Ec;
      int Mc = (int)(((long)E_ - e0 < Ec) ? ((long)E_ - e0) : Ec);
      dim3 g2m(2, Mc / 128), g64(1, Mc / 64);
      mg2_k<true, true, true, true><<<g2m, 256, 0, stream>>>(
          FUb, FVb, src + e0, dst + e0, fcW1t, fc_b1, C1b, Mc, 256, 256, 256, 256);
      mgemm_k<true, true, true><<<g64, 256, 0, stream>>>(
          C1b, fcW2t, fc_b2, C3b, Mc, 64, 256, 256, 128, ea_cur, e0);
      eu_fused_k<<<Mc / 128, 256, 0, stream>>>(
          C3b, euW1t, eu_b1, euW2t, eu_b2, EAp, eab, e0);
    }

    x_cur = Hb;
    ea_cur = EAp;
  }

  // outputs: [out (N*128) | ea (in place) | out (N*128)]
  hipMemcpyAsync(out, x_cur, (size_t)N_ * 128 * 4, hipMemcpyDeviceToDevice, stream);
  hipMemcpyAsync(out + (size_t)N_ * 128 + (size_t)E_ * 64, x_cur,
                 (size_t)N_ * 128 * 4, hipMemcpyDeviceToDevice, stream);
}